// Round 1
// baseline (4264.422 us; speedup 1.0000x reference)
//
#include <hip/hip_runtime.h>
#include <math.h>

// ImplicitFlowDecoder: fused megakernel, fp32 baseline.
// 32 points per block, 256 threads (4 waves). Activations in LDS [C][STRIDE],
// register-blocked GEMMs (4 points x 4 outs per thread), weights from global (L2-hot).

#define STRIDE 36           // LDS row stride in floats (16B-aligned float4 reads)
#define NPTS 32             // points per block
#define NPOINTS_TOTAL (2*384*512)
#define NBLOCKS (NPOINTS_TOTAL/NPTS)

__device__ __forceinline__ float sigmoidf_(float x) { return 1.0f / (1.0f + expf(-x)); }
__device__ __forceinline__ float geluf_(float x) {
    // exact gelu: 0.5*x*(1+erf(x/sqrt(2)))
    return 0.5f * x * (1.0f + erff(x * 0.70710678118654752f));
}

// LDS float4 read of activations at (row i, points pl4..pl4+3)
__device__ __forceinline__ float4 ldsA(const float* s, int i, int pl4) {
    return *reinterpret_cast<const float4*>(s + i * STRIDE + pl4);
}

// acc[k][j] += sum_i in[i][pl4+k] * W[(wrow+i)*ldw + wcol + o0 + j]
template <int NO>
__device__ __forceinline__ void gemm_acc(float (&acc)[4][NO], const float* sIn, int I,
                                         const float* __restrict__ W, int ldw, int wcol, int wrow,
                                         int o0, int pl4) {
#pragma unroll 2
    for (int i = 0; i < I; ++i) {
        const float4 a = ldsA(sIn, i, pl4);
        const float* wp = W + (size_t)(wrow + i) * ldw + wcol + o0;
        float w[NO];
        if constexpr (NO == 4) {
            const float4 t = *reinterpret_cast<const float4*>(wp);
            w[0] = t.x; w[1] = t.y; w[2] = t.z; w[3] = t.w;
        } else {
            const float2 t = *reinterpret_cast<const float2*>(wp);
            w[0] = t.x; w[1] = t.y;
        }
#pragma unroll
        for (int j = 0; j < NO; ++j) {
            acc[0][j] = fmaf(a.x, w[j], acc[0][j]);
            acc[1][j] = fmaf(a.y, w[j], acc[1][j]);
            acc[2][j] = fmaf(a.z, w[j], acc[2][j]);
            acc[3][j] = fmaf(a.w, w[j], acc[3][j]);
        }
    }
}

__global__ void __launch_bounds__(256, 2)
ifd_kernel(const float* __restrict__ feat_s8, const float* __restrict__ feat1_s8,
           const float* __restrict__ feat_s16, const float* __restrict__ ctx_s8,
           const float* __restrict__ coarse_flow,
           const float* __restrict__ ctx_w, const float* __restrict__ ctx_b,
           const float* __restrict__ gate1,
           const float* __restrict__ ffn1_w1, const float* __restrict__ ffn1_b1,
           const float* __restrict__ ffn1_w2, const float* __restrict__ ffn1_b2,
           const float* __restrict__ s8_w, const float* __restrict__ s8_b,
           const float* __restrict__ gate2,
           const float* __restrict__ ffn2_w1, const float* __restrict__ ffn2_b1,
           const float* __restrict__ ffn2_w2, const float* __restrict__ ffn2_b2,
           const float* __restrict__ hw1, const float* __restrict__ hb1,
           const float* __restrict__ hw2, const float* __restrict__ hb2,
           const float* __restrict__ hw3, const float* __restrict__ hb3,
           const float* __restrict__ hw4, const float* __restrict__ hb4,
           float* __restrict__ out) {
    // LDS: 3 x (128 x STRIDE) activation buffers + scal[4][32] + coarse_px[2][32] + 3 coord sets [6][32]
    __shared__ float smem[3 * 128 * STRIDE + 4 * 32 + 2 * 32 + 3 * 6 * 32];
    float* sH = smem;                       // buffer A (128 rows)
    float* sF = smem + 128 * STRIDE;        // buffer B (128 rows) : f16, later f1w
    float* sU = smem + 256 * STRIDE;        // buffer C (128 rows)
    float* sScal = smem + 384 * STRIDE;     // [4][32]: cn_x, cn_y, cfn_x, cfn_y
    float* sCps = sScal + 128;              // [2][32]: coarse flow in full-res pixels
    float* sCrd = sCps + 64;                // 3 sets x [6][32] (x0,x1,y0,y1 as int; wx,wy)

    const int t = threadIdx.x;
    const int p = t & 31;
    const int cg = t >> 5;
    const int q = blockIdx.x * NPTS + p;
    const int b = q / 196608;               // 384*512
    const int rem = q - b * 196608;
    const int gy = rem >> 9;
    const int gx = rem & 511;

    const float CHI = 1.0f - 1e-6f;         // EPS clip bound

    // ---------- Phase A: per-point coordinates, coarse flow sample, warp (threads 0..31)
    if (t < 32) {
        float cnx = fminf(fmaxf(2.0f * ((float)gx + 0.5f) / 512.0f - 1.0f, -CHI), CHI);
        float cny = fminf(fmaxf(2.0f * ((float)gy + 0.5f) / 384.0f - 1.0f, -CHI), CHI);

        auto mkc = [](float cn, float Sf, int Smax, int& i0, int& i1, float& w) {
            float x = fminf(fmaxf(((cn + 1.0f) * Sf - 1.0f) * 0.5f, 0.0f), Sf - 1.0f);
            float xf = floorf(x);
            w = x - xf;
            i0 = (int)xf;
            i1 = (i0 + 1 > Smax) ? Smax : i0 + 1;
        };
        auto storeSet = [&](int s, int x0, int x1, int y0, int y1, float wx, float wy) {
            int* ib = (int*)(sCrd + s * 192);
            ib[0 * 32 + t] = x0; ib[1 * 32 + t] = x1; ib[2 * 32 + t] = y0; ib[3 * 32 + t] = y1;
            sCrd[s * 192 + 4 * 32 + t] = wx; sCrd[s * 192 + 5 * 32 + t] = wy;
        };

        // set 0: s8 grid (W=64, H=48)
        int x0, x1, y0, y1; float wx, wy;
        mkc(cnx, 64.0f, 63, x0, x1, wx);
        mkc(cny, 48.0f, 47, y0, y1, wy);
        storeSet(0, x0, x1, y0, y1, wx, wy);

        // set 1: s16 grid (W=32, H=24)
        int X0, X1, Y0, Y1; float WX, WY;
        mkc(cnx, 32.0f, 31, X0, X1, WX);
        mkc(cny, 24.0f, 23, Y0, Y1, WY);
        storeSet(1, X0, X1, Y0, Y1, WX, WY);

        // coarse_flow sample at set-0 coords (C=2), scale by 8 to full-res pixels
        const float w00 = (1.0f - wx) * (1.0f - wy), w01 = wx * (1.0f - wy);
        const float w10 = (1.0f - wx) * wy, w11 = wx * wy;
        const int i00 = y0 * 64 + x0, i01 = y0 * 64 + x1, i10 = y1 * 64 + x0, i11 = y1 * 64 + x1;
        const float* cf = coarse_flow + (size_t)b * (2 * 48 * 64);
        float c0 = (cf[i00] * w00 + cf[i01] * w01 + cf[i10] * w10 + cf[i11] * w11) * 8.0f;
        const float* cf1 = cf + 48 * 64;
        float c1 = (cf1[i00] * w00 + cf1[i01] * w01 + cf1[i10] * w10 + cf1[i11] * w11) * 8.0f;
        sCps[t] = c0; sCps[32 + t] = c1;
        sScal[t] = cnx; sScal[32 + t] = cny;
        sScal[64 + t] = c0 / 512.0f; sScal[96 + t] = c1 / 384.0f;

        // warped coords for feat1_s8 (set 2, s8 grid)
        float wxn = fminf(fmaxf(cnx + 2.0f * c0 / 512.0f, -CHI), CHI);
        float wyn = fminf(fmaxf(cny + 2.0f * c1 / 384.0f, -CHI), CHI);
        int u0, u1, v0, v1; float uw, vw;
        mkc(wxn, 64.0f, 63, u0, u1, uw);
        mkc(wyn, 48.0f, 47, v0, v1, vw);
        storeSet(2, u0, u1, v0, v1, uw, vw);
    }
    __syncthreads();

    const int ol = t & 31;
    const int pl4 = (t >> 5) * 4;
    const int o04 = ol * 4;

    // helper: sample a 128-channel feature map with coord set -> dst LDS buffer
    auto sample128 = [&](const float* __restrict__ base, int hw, int Wd, int set, float* dst) {
        const int* ib = (const int*)(sCrd + set * 192);
        int x0 = ib[p], x1 = ib[32 + p], y0 = ib[64 + p], y1 = ib[96 + p];
        float wx = sCrd[set * 192 + 128 + p], wy = sCrd[set * 192 + 160 + p];
        float w00 = (1.0f - wx) * (1.0f - wy), w01 = wx * (1.0f - wy);
        float w10 = (1.0f - wx) * wy, w11 = wx * wy;
        int i00 = y0 * Wd + x0, i01 = y0 * Wd + x1, i10 = y1 * Wd + x0, i11 = y1 * Wd + x1;
        const float* fb = base + (size_t)b * 128 * hw;
#pragma unroll 4
        for (int k = 0; k < 16; ++k) {
            int c = cg * 16 + k;
            const float* ch = fb + (size_t)c * hw;
            dst[c * STRIDE + p] = ch[i00] * w00 + ch[i01] * w01 + ch[i10] * w10 + ch[i11] * w11;
        }
    };

    // ---------- Phase B: bilinear sampling. f8 -> sH, fctx -> sU[0:64], f16 -> sF
    sample128(feat_s8, 48 * 64, 64, 0, sH);
    sample128(feat_s16, 24 * 32, 32, 1, sF);
    {
        const int* ib = (const int*)(sCrd);
        int x0 = ib[p], x1 = ib[32 + p], y0 = ib[64 + p], y1 = ib[96 + p];
        float wx = sCrd[128 + p], wy = sCrd[160 + p];
        float w00 = (1.0f - wx) * (1.0f - wy), w01 = wx * (1.0f - wy);
        float w10 = (1.0f - wx) * wy, w11 = wx * wy;
        int i00 = y0 * 64 + x0, i01 = y0 * 64 + x1, i10 = y1 * 64 + x0, i11 = y1 * 64 + x1;
        const float* fb = ctx_s8 + (size_t)b * 64 * 3072;
#pragma unroll 4
        for (int k = 0; k < 8; ++k) {
            int c = cg * 8 + k;
            const float* ch = fb + (size_t)c * 3072;
            sU[c * STRIDE + p] = ch[i00] * w00 + ch[i01] * w01 + ch[i10] * w10 + ch[i11] * w11;
        }
    }
    __syncthreads();

    // ---------- P3: t1 = fctx @ ctx_w + ctx_b ; h2 = f8 + sig(g1)*t1  (in sU[0:64] -> sH)
    {
        float acc[4][4] = {};
        gemm_acc<4>(acc, sU, 64, ctx_w, 128, 0, 0, o04, pl4);
#pragma unroll
        for (int j = 0; j < 4; ++j) {
            int o = o04 + j;
            float g = sigmoidf_(gate1[o]);
            float bb = ctx_b[o];
#pragma unroll
            for (int k = 0; k < 4; ++k)
                sH[o * STRIDE + pl4 + k] += g * (acc[k][j] + bb);
        }
    }
    __syncthreads();

    // ---------- P4: ffn1 (128 -> 256 gelu -> 128), 256-wide intermediate in two halves
    {
        float h2b[4][4] = {};
        {   // u half 1
            float acc[4][4] = {};
            gemm_acc<4>(acc, sH, 128, ffn1_w1, 256, 0, 0, o04, pl4);
#pragma unroll
            for (int j = 0; j < 4; ++j) {
                float bb = ffn1_b1[o04 + j];
#pragma unroll
                for (int k = 0; k < 4; ++k)
                    sU[(o04 + j) * STRIDE + pl4 + k] = geluf_(acc[k][j] + bb);
            }
        }
        __syncthreads();
        gemm_acc<4>(h2b, sU, 128, ffn1_w2, 128, 0, 0, o04, pl4);
        __syncthreads();
        {   // u half 2
            float acc[4][4] = {};
            gemm_acc<4>(acc, sH, 128, ffn1_w1, 256, 128, 0, o04, pl4);
#pragma unroll
            for (int j = 0; j < 4; ++j) {
                float bb = ffn1_b1[128 + o04 + j];
#pragma unroll
                for (int k = 0; k < 4; ++k)
                    sU[(o04 + j) * STRIDE + pl4 + k] = geluf_(acc[k][j] + bb);
            }
        }
        __syncthreads();
        gemm_acc<4>(h2b, sU, 128, ffn1_w2, 128, 0, 128, o04, pl4);
#pragma unroll
        for (int j = 0; j < 4; ++j) {
            float bb = ffn1_b2[o04 + j];
#pragma unroll
            for (int k = 0; k < 4; ++k)
                sH[(o04 + j) * STRIDE + pl4 + k] = h2b[k][j] + bb;
        }
    }
    __syncthreads();

    // ---------- P6: t2 = h2 @ s8_w + s8_b ; h3 = f16 + sig(g2)*t2  (sH -> sU, reads sF)
    {
        float acc[4][4] = {};
        gemm_acc<4>(acc, sH, 128, s8_w, 128, 0, 0, o04, pl4);
#pragma unroll
        for (int j = 0; j < 4; ++j) {
            int o = o04 + j;
            float g = sigmoidf_(gate2[o]);
            float bb = s8_b[o];
#pragma unroll
            for (int k = 0; k < 4; ++k)
                sU[o * STRIDE + pl4 + k] = sF[o * STRIDE + pl4 + k] + g * (acc[k][j] + bb);
        }
    }
    __syncthreads();

    // ---------- P7: ffn2 (sU=h3 -> fused in sU), intermediate halves in sH
    {
        float fac[4][4] = {};
        {
            float acc[4][4] = {};
            gemm_acc<4>(acc, sU, 128, ffn2_w1, 256, 0, 0, o04, pl4);
#pragma unroll
            for (int j = 0; j < 4; ++j) {
                float bb = ffn2_b1[o04 + j];
#pragma unroll
                for (int k = 0; k < 4; ++k)
                    sH[(o04 + j) * STRIDE + pl4 + k] = geluf_(acc[k][j] + bb);
            }
        }
        __syncthreads();
        gemm_acc<4>(fac, sH, 128, ffn2_w2, 128, 0, 0, o04, pl4);
        __syncthreads();
        {
            float acc[4][4] = {};
            gemm_acc<4>(acc, sU, 128, ffn2_w1, 256, 128, 0, o04, pl4);
#pragma unroll
            for (int j = 0; j < 4; ++j) {
                float bb = ffn2_b1[128 + o04 + j];
#pragma unroll
                for (int k = 0; k < 4; ++k)
                    sH[(o04 + j) * STRIDE + pl4 + k] = geluf_(acc[k][j] + bb);
            }
        }
        __syncthreads();
        gemm_acc<4>(fac, sH, 128, ffn2_w2, 128, 0, 128, o04, pl4);
#pragma unroll
        for (int j = 0; j < 4; ++j) {
            float bb = ffn2_b2[o04 + j];
#pragma unroll
            for (int k = 0; k < 4; ++k)
                sU[(o04 + j) * STRIDE + pl4 + k] = fac[k][j] + bb;   // fused
        }
    }
    __syncthreads();

    // ---------- P9: sample f1w (warped, set 2) -> sF
    sample128(feat1_s8, 48 * 64, 64, 2, sF);
    __syncthreads();

    // ---------- P10: head layer 1 (260 -> 256 relu) in halves, then hw2 (256 -> 128 relu)
    {
        float a2[4][4] = {};
        {   // a1 half 1 (cols 0..127)
            float acc[4][4] = {};
            gemm_acc<4>(acc, sU, 128, hw1, 256, 0, 0, o04, pl4);      // fused  -> rows 0..127
            gemm_acc<4>(acc, sF, 128, hw1, 256, 0, 128, o04, pl4);    // f1w    -> rows 128..255
#pragma unroll
            for (int jj = 0; jj < 4; ++jj) {                          // scal   -> rows 256..259
                const float4 sv = *reinterpret_cast<const float4*>(sScal + jj * 32 + pl4);
                const float4 wv = *reinterpret_cast<const float4*>(hw1 + (size_t)(256 + jj) * 256 + o04);
                float svk[4] = {sv.x, sv.y, sv.z, sv.w};
                float wvj[4] = {wv.x, wv.y, wv.z, wv.w};
#pragma unroll
                for (int j = 0; j < 4; ++j)
#pragma unroll
                    for (int k = 0; k < 4; ++k)
                        acc[k][j] = fmaf(svk[k], wvj[j], acc[k][j]);
            }
#pragma unroll
            for (int j = 0; j < 4; ++j) {
                float bb = hb1[o04 + j];
#pragma unroll
                for (int k = 0; k < 4; ++k)
                    sH[(o04 + j) * STRIDE + pl4 + k] = fmaxf(acc[k][j] + bb, 0.0f);
            }
        }
        __syncthreads();
        gemm_acc<4>(a2, sH, 128, hw2, 128, 0, 0, o04, pl4);
        __syncthreads();
        {   // a1 half 2 (cols 128..255)
            float acc[4][4] = {};
            gemm_acc<4>(acc, sU, 128, hw1, 256, 128, 0, o04, pl4);
            gemm_acc<4>(acc, sF, 128, hw1, 256, 128, 128, o04, pl4);
#pragma unroll
            for (int jj = 0; jj < 4; ++jj) {
                const float4 sv = *reinterpret_cast<const float4*>(sScal + jj * 32 + pl4);
                const float4 wv = *reinterpret_cast<const float4*>(hw1 + (size_t)(256 + jj) * 256 + 128 + o04);
                float svk[4] = {sv.x, sv.y, sv.z, sv.w};
                float wvj[4] = {wv.x, wv.y, wv.z, wv.w};
#pragma unroll
                for (int j = 0; j < 4; ++j)
#pragma unroll
                    for (int k = 0; k < 4; ++k)
                        acc[k][j] = fmaf(svk[k], wvj[j], acc[k][j]);
            }
#pragma unroll
            for (int j = 0; j < 4; ++j) {
                float bb = hb1[128 + o04 + j];
#pragma unroll
                for (int k = 0; k < 4; ++k)
                    sH[(o04 + j) * STRIDE + pl4 + k] = fmaxf(acc[k][j] + bb, 0.0f);
            }
        }
        __syncthreads();
        gemm_acc<4>(a2, sH, 128, hw2, 128, 0, 128, o04, pl4);
#pragma unroll
        for (int j = 0; j < 4; ++j) {
            float bb = hb2[o04 + j];
#pragma unroll
            for (int k = 0; k < 4; ++k)
                sU[(o04 + j) * STRIDE + pl4 + k] = fmaxf(a2[k][j] + bb, 0.0f);
        }
    }
    __syncthreads();

    // ---------- P12: hw3 (128 -> 64 relu) : sU -> sH rows 0..63
    {
        float acc[4][2] = {};
        const int o02 = ol * 2;
        gemm_acc<2>(acc, sU, 128, hw3, 64, 0, 0, o02, pl4);
#pragma unroll
        for (int j = 0; j < 2; ++j) {
            float bb = hb3[o02 + j];
#pragma unroll
            for (int k = 0; k < 4; ++k)
                sH[(o02 + j) * STRIDE + pl4 + k] = fmaxf(acc[k][j] + bb, 0.0f);
        }
    }
    __syncthreads();

    // ---------- P13: hw4 (64 -> 2), flow = coarse_px + delta * [512, 384], write out
    if (t < 64) {
        const int pp = t >> 1;
        const int j = t & 1;
        float d = hb4[j];
#pragma unroll 8
        for (int i = 0; i < 64; ++i)
            d = fmaf(sH[i * STRIDE + pp], hw4[i * 2 + j], d);
        const int qq = blockIdx.x * NPTS + pp;
        const int bb = qq / 196608;
        const int rr = qq - bb * 196608;
        const int gyy = rr >> 9;
        const int gxx = rr & 511;
        float flow = sCps[j * 32 + pp] + d * (j == 0 ? 512.0f : 384.0f);
        out[(((size_t)bb * 2 + j) * 384 + gyy) * 512 + gxx] = flow;
    }
}

extern "C" void kernel_launch(void* const* d_in, const int* in_sizes, int n_in,
                              void* d_out, int out_size, void* d_ws, size_t ws_size,
                              hipStream_t stream) {
    // setup_inputs() order: 0 img (unused), 1 feat_s8, 2 feat1_s8, 3 feat_s16, 4 ctx_s8,
    // 5 coarse_flow, 6 ctx_w, 7 ctx_b, 8 gate1, 9 ffn1_w1, 10 ffn1_b1, 11 ffn1_w2,
    // 12 ffn1_b2, 13 s8_w, 14 s8_b, 15 gate2, 16 ffn2_w1, 17 ffn2_b1, 18 ffn2_w2,
    // 19 ffn2_b2, 20 hw1, 21 hb1, 22 hw2, 23 hb2, 24 hw3, 25 hb3, 26 hw4, 27 hb4
    const float* feat_s8 = (const float*)d_in[1];
    const float* feat1_s8 = (const float*)d_in[2];
    const float* feat_s16 = (const float*)d_in[3];
    const float* ctx_s8 = (const float*)d_in[4];
    const float* coarse_flow = (const float*)d_in[5];
    const float* ctx_w = (const float*)d_in[6];
    const float* ctx_b = (const float*)d_in[7];
    const float* gate1 = (const float*)d_in[8];
    const float* ffn1_w1 = (const float*)d_in[9];
    const float* ffn1_b1 = (const float*)d_in[10];
    const float* ffn1_w2 = (const float*)d_in[11];
    const float* ffn1_b2 = (const float*)d_in[12];
    const float* s8_w = (const float*)d_in[13];
    const float* s8_b = (const float*)d_in[14];
    const float* gate2 = (const float*)d_in[15];
    const float* ffn2_w1 = (const float*)d_in[16];
    const float* ffn2_b1 = (const float*)d_in[17];
    const float* ffn2_w2 = (const float*)d_in[18];
    const float* ffn2_b2 = (const float*)d_in[19];
    const float* hw1 = (const float*)d_in[20];
    const float* hb1 = (const float*)d_in[21];
    const float* hw2 = (const float*)d_in[22];
    const float* hb2 = (const float*)d_in[23];
    const float* hw3 = (const float*)d_in[24];
    const float* hb3 = (const float*)d_in[25];
    const float* hw4 = (const float*)d_in[26];
    const float* hb4 = (const float*)d_in[27];
    float* out = (float*)d_out;

    ifd_kernel<<<dim3(NBLOCKS), dim3(256), 0, stream>>>(
        feat_s8, feat1_s8, feat_s16, ctx_s8, coarse_flow,
        ctx_w, ctx_b, gate1, ffn1_w1, ffn1_b1, ffn1_w2, ffn1_b2,
        s8_w, s8_b, gate2, ffn2_w1, ffn2_b1, ffn2_w2, ffn2_b2,
        hw1, hb1, hw2, hb2, hw3, hb3, hw4, hb4, out);
}

// Round 2
// 3508.593 us; speedup vs baseline: 1.2154x; 1.2154x over previous
//
#include <hip/hip_runtime.h>
#include <math.h>

// ImplicitFlowDecoder: fused megakernel, fp32, round 2.
// 32 points/block, 256 threads. TWO LDS activation buffers (39.9KB -> 4 blocks/CU),
// XOR-swizzled cols (bank-conflict-free b128 epilogue stores), unroll-4 GEMMs.

#define STRIDE 36           // LDS row stride in floats
#define NPTS 32
#define NPOINTS_TOTAL (2*384*512)
#define NBLOCKS (NPOINTS_TOTAL/NPTS)

__device__ __forceinline__ float sigmoidf_(float x) { return 1.0f / (1.0f + expf(-x)); }
__device__ __forceinline__ float geluf_(float x) {
    return 0.5f * x * (1.0f + erff(x * 0.70710678118654752f));
}
// per-row XOR value for 4-col block swizzle
__device__ __forceinline__ int swzb(int row) { return ((row >> 2) & 7) << 2; }

__device__ __forceinline__ float4 ld4(const float* buf, int row, int pl4) {
    return *reinterpret_cast<const float4*>(buf + row * STRIDE + (pl4 ^ swzb(row)));
}
__device__ __forceinline__ void st4(float* buf, int row, int pl4, float4 v) {
    *reinterpret_cast<float4*>(buf + row * STRIDE + (pl4 ^ swzb(row))) = v;
}

// acc[k][j] += sum_{i<I} act[i][pl4+k] * W[(wrow+i)*ldw + wcol + o0 + j]
template <int I, int NO>
__device__ __forceinline__ void gemm_acc(float (&acc)[4][NO], const float* sIn,
                                         const float* __restrict__ W, int ldw, int wcol, int wrow,
                                         int o0, int pl4) {
    const float* wp0 = W + (size_t)wrow * ldw + wcol + o0;
#pragma unroll 4
    for (int i = 0; i < I; ++i) {
        const float4 a = *reinterpret_cast<const float4*>(sIn + i * STRIDE + (pl4 ^ swzb(i)));
        const float* wp = wp0 + (size_t)i * ldw;
        float w[NO];
        if constexpr (NO == 4) {
            const float4 t = *reinterpret_cast<const float4*>(wp);
            w[0] = t.x; w[1] = t.y; w[2] = t.z; w[3] = t.w;
        } else {
            const float2 t = *reinterpret_cast<const float2*>(wp);
            w[0] = t.x; w[1] = t.y;
        }
#pragma unroll
        for (int j = 0; j < NO; ++j) {
            acc[0][j] = fmaf(a.x, w[j], acc[0][j]);
            acc[1][j] = fmaf(a.y, w[j], acc[1][j]);
            acc[2][j] = fmaf(a.z, w[j], acc[2][j]);
            acc[3][j] = fmaf(a.w, w[j], acc[3][j]);
        }
    }
}

__global__ void __launch_bounds__(256, 4)
ifd_kernel(const float* __restrict__ feat_s8, const float* __restrict__ feat1_s8,
           const float* __restrict__ feat_s16, const float* __restrict__ ctx_s8,
           const float* __restrict__ coarse_flow,
           const float* __restrict__ ctx_w, const float* __restrict__ ctx_b,
           const float* __restrict__ gate1,
           const float* __restrict__ ffn1_w1, const float* __restrict__ ffn1_b1,
           const float* __restrict__ ffn1_w2, const float* __restrict__ ffn1_b2,
           const float* __restrict__ s8_w, const float* __restrict__ s8_b,
           const float* __restrict__ gate2,
           const float* __restrict__ ffn2_w1, const float* __restrict__ ffn2_b1,
           const float* __restrict__ ffn2_w2, const float* __restrict__ ffn2_b2,
           const float* __restrict__ hw1, const float* __restrict__ hb1,
           const float* __restrict__ hw2, const float* __restrict__ hb2,
           const float* __restrict__ hw3, const float* __restrict__ hb3,
           const float* __restrict__ hw4, const float* __restrict__ hb4,
           float* __restrict__ out) {
    // 2 x (128 x STRIDE) activation buffers + scal[4][32] + coarse_px[2][32] + 3 coord sets
    __shared__ __align__(16) float smem[2 * 128 * STRIDE + 128 + 64 + 3 * 6 * 32];
    float* sA = smem;
    float* sB = smem + 128 * STRIDE;
    float* sScal = smem + 2 * 128 * STRIDE;   // [4][32]: cn_x, cn_y, cfn_x, cfn_y
    float* sCps = sScal + 128;                // [2][32]: coarse flow in full-res px
    float* sCrd = sCps + 64;                  // 3 sets x [6][32]

    const int t = threadIdx.x;
    const int p = t & 31;
    const int cg = t >> 5;                    // 0..7 (half-wave id)
    const int b = (blockIdx.x * NPTS + p) / 196608;
    const int rem = (blockIdx.x * NPTS + p) - b * 196608;
    const int gy = rem >> 9;
    const int gx = rem & 511;

    const float CHI = 1.0f - 1e-6f;

    // ---------- coords, coarse flow, warp (threads 0..31)
    if (t < 32) {
        float cnx = fminf(fmaxf(2.0f * ((float)gx + 0.5f) / 512.0f - 1.0f, -CHI), CHI);
        float cny = fminf(fmaxf(2.0f * ((float)gy + 0.5f) / 384.0f - 1.0f, -CHI), CHI);

        auto mkc = [](float cn, float Sf, int Smax, int& i0, int& i1, float& w) {
            float x = fminf(fmaxf(((cn + 1.0f) * Sf - 1.0f) * 0.5f, 0.0f), Sf - 1.0f);
            float xf = floorf(x);
            w = x - xf;
            i0 = (int)xf;
            i1 = (i0 + 1 > Smax) ? Smax : i0 + 1;
        };
        auto storeSet = [&](int s, int x0, int x1, int y0, int y1, float wx, float wy) {
            int* ib = (int*)(sCrd + s * 192);
            ib[t] = x0; ib[32 + t] = x1; ib[64 + t] = y0; ib[96 + t] = y1;
            sCrd[s * 192 + 128 + t] = wx; sCrd[s * 192 + 160 + t] = wy;
        };

        int x0, x1, y0, y1; float wx, wy;
        mkc(cnx, 64.0f, 63, x0, x1, wx);
        mkc(cny, 48.0f, 47, y0, y1, wy);
        storeSet(0, x0, x1, y0, y1, wx, wy);

        int X0, X1, Y0, Y1; float WX, WY;
        mkc(cnx, 32.0f, 31, X0, X1, WX);
        mkc(cny, 24.0f, 23, Y0, Y1, WY);
        storeSet(1, X0, X1, Y0, Y1, WX, WY);

        const float w00 = (1.0f - wx) * (1.0f - wy), w01 = wx * (1.0f - wy);
        const float w10 = (1.0f - wx) * wy, w11 = wx * wy;
        const int i00 = y0 * 64 + x0, i01 = y0 * 64 + x1, i10 = y1 * 64 + x0, i11 = y1 * 64 + x1;
        const float* cf = coarse_flow + (size_t)b * (2 * 48 * 64);
        float c0 = (cf[i00] * w00 + cf[i01] * w01 + cf[i10] * w10 + cf[i11] * w11) * 8.0f;
        const float* cf1 = cf + 48 * 64;
        float c1 = (cf1[i00] * w00 + cf1[i01] * w01 + cf1[i10] * w10 + cf1[i11] * w11) * 8.0f;
        sCps[t] = c0; sCps[32 + t] = c1;
        sScal[t] = cnx; sScal[32 + t] = cny;
        sScal[64 + t] = c0 / 512.0f; sScal[96 + t] = c1 / 384.0f;

        float wxn = fminf(fmaxf(cnx + 2.0f * c0 / 512.0f, -CHI), CHI);
        float wyn = fminf(fmaxf(cny + 2.0f * c1 / 384.0f, -CHI), CHI);
        int u0, u1, v0, v1; float uw, vw;
        mkc(wxn, 64.0f, 63, u0, u1, uw);
        mkc(wyn, 48.0f, 47, v0, v1, vw);
        storeSet(2, u0, u1, v0, v1, uw, vw);
    }
    __syncthreads();

    const int ol = t & 31;
    const int pl4 = cg * 4;        // 0,4,...,28 : this half-wave's 4 points
    const int o04 = ol * 4;        // this lane's 4 output channels

    auto sample128 = [&](const float* __restrict__ base, int hw, int Wd, int set, float* dst) {
        const int* ib = (const int*)(sCrd + set * 192);
        int x0 = ib[p], x1 = ib[32 + p], y0 = ib[64 + p], y1 = ib[96 + p];
        float wx = sCrd[set * 192 + 128 + p], wy = sCrd[set * 192 + 160 + p];
        float w00 = (1.0f - wx) * (1.0f - wy), w01 = wx * (1.0f - wy);
        float w10 = (1.0f - wx) * wy, w11 = wx * wy;
        int i00 = y0 * Wd + x0, i01 = y0 * Wd + x1, i10 = y1 * Wd + x0, i11 = y1 * Wd + x1;
        const float* fb = base + (size_t)b * 128 * hw;
#pragma unroll 4
        for (int k = 0; k < 16; ++k) {
            int c = cg * 16 + k;
            const float* ch = fb + (size_t)c * hw;
            dst[c * STRIDE + ((p & 3) | ((p & ~3) ^ swzb(c)))] =
                ch[i00] * w00 + ch[i01] * w01 + ch[i10] * w10 + ch[i11] * w11;
        }
    };

    // ---------- sample f8 -> A, fctx -> B[0:64]
    sample128(feat_s8, 48 * 64, 64, 0, sA);
    {
        const int* ib = (const int*)(sCrd);
        int x0 = ib[p], x1 = ib[32 + p], y0 = ib[64 + p], y1 = ib[96 + p];
        float wx = sCrd[128 + p], wy = sCrd[160 + p];
        float w00 = (1.0f - wx) * (1.0f - wy), w01 = wx * (1.0f - wy);
        float w10 = (1.0f - wx) * wy, w11 = wx * wy;
        int i00 = y0 * 64 + x0, i01 = y0 * 64 + x1, i10 = y1 * 64 + x0, i11 = y1 * 64 + x1;
        const float* fb = ctx_s8 + (size_t)b * 64 * 3072;
#pragma unroll 4
        for (int k = 0; k < 8; ++k) {
            int c = cg * 8 + k;
            const float* ch = fb + (size_t)c * 3072;
            sB[c * STRIDE + ((p & 3) | ((p & ~3) ^ swzb(c)))] =
                ch[i00] * w00 + ch[i01] * w01 + ch[i10] * w10 + ch[i11] * w11;
        }
    }
    __syncthreads();

    // ---------- P3: A(h2_in) = f8 + sig(g1)*(fctx @ ctx_w + ctx_b)
    {
        float acc[4][4] = {};
        gemm_acc<64, 4>(acc, sB, ctx_w, 128, 0, 0, o04, pl4);
        const float4 g4 = *reinterpret_cast<const float4*>(gate1 + o04);
        const float4 b4 = *reinterpret_cast<const float4*>(ctx_b + o04);
        const float gs[4] = {sigmoidf_(g4.x), sigmoidf_(g4.y), sigmoidf_(g4.z), sigmoidf_(g4.w)};
        const float bs[4] = {b4.x, b4.y, b4.z, b4.w};
#pragma unroll
        for (int j = 0; j < 4; ++j) {
            float4 v = ld4(sA, o04 + j, pl4);
            v.x += gs[j] * (acc[0][j] + bs[j]);
            v.y += gs[j] * (acc[1][j] + bs[j]);
            v.z += gs[j] * (acc[2][j] + bs[j]);
            v.w += gs[j] * (acc[3][j] + bs[j]);
            st4(sA, o04 + j, pl4, v);
        }
    }
    __syncthreads();

    // ---------- ffn1: A -> A  (scratch B)
    {
        float h2b[4][4] = {};
        {
            float acc[4][4] = {};
            gemm_acc<128, 4>(acc, sA, ffn1_w1, 256, 0, 0, o04, pl4);
            const float4 b4 = *reinterpret_cast<const float4*>(ffn1_b1 + o04);
            const float bs[4] = {b4.x, b4.y, b4.z, b4.w};
#pragma unroll
            for (int j = 0; j < 4; ++j)
                st4(sB, o04 + j, pl4, make_float4(geluf_(acc[0][j] + bs[j]), geluf_(acc[1][j] + bs[j]),
                                                  geluf_(acc[2][j] + bs[j]), geluf_(acc[3][j] + bs[j])));
        }
        __syncthreads();
        gemm_acc<128, 4>(h2b, sB, ffn1_w2, 128, 0, 0, o04, pl4);
        __syncthreads();
        {
            float acc[4][4] = {};
            gemm_acc<128, 4>(acc, sA, ffn1_w1, 256, 128, 0, o04, pl4);
            const float4 b4 = *reinterpret_cast<const float4*>(ffn1_b1 + 128 + o04);
            const float bs[4] = {b4.x, b4.y, b4.z, b4.w};
#pragma unroll
            for (int j = 0; j < 4; ++j)
                st4(sB, o04 + j, pl4, make_float4(geluf_(acc[0][j] + bs[j]), geluf_(acc[1][j] + bs[j]),
                                                  geluf_(acc[2][j] + bs[j]), geluf_(acc[3][j] + bs[j])));
        }
        __syncthreads();
        gemm_acc<128, 4>(h2b, sB, ffn1_w2, 128, 0, 128, o04, pl4);
        {
            const float4 b4 = *reinterpret_cast<const float4*>(ffn1_b2 + o04);
            const float bs[4] = {b4.x, b4.y, b4.z, b4.w};
#pragma unroll
            for (int j = 0; j < 4; ++j)
                st4(sA, o04 + j, pl4, make_float4(h2b[0][j] + bs[j], h2b[1][j] + bs[j],
                                                  h2b[2][j] + bs[j], h2b[3][j] + bs[j]));
        }
    }
    __syncthreads();

    // ---------- sample f16 -> B
    sample128(feat_s16, 24 * 32, 32, 1, sB);
    __syncthreads();

    // ---------- P6: B(h3) = f16 + sig(g2)*(A @ s8_w + s8_b)
    {
        float acc[4][4] = {};
        gemm_acc<128, 4>(acc, sA, s8_w, 128, 0, 0, o04, pl4);
        const float4 g4 = *reinterpret_cast<const float4*>(gate2 + o04);
        const float4 b4 = *reinterpret_cast<const float4*>(s8_b + o04);
        const float gs[4] = {sigmoidf_(g4.x), sigmoidf_(g4.y), sigmoidf_(g4.z), sigmoidf_(g4.w)};
        const float bs[4] = {b4.x, b4.y, b4.z, b4.w};
#pragma unroll
        for (int j = 0; j < 4; ++j) {
            float4 v = ld4(sB, o04 + j, pl4);
            v.x += gs[j] * (acc[0][j] + bs[j]);
            v.y += gs[j] * (acc[1][j] + bs[j]);
            v.z += gs[j] * (acc[2][j] + bs[j]);
            v.w += gs[j] * (acc[3][j] + bs[j]);
            st4(sB, o04 + j, pl4, v);
        }
    }
    __syncthreads();

    // ---------- ffn2: B(h3) -> B(fused)  (scratch A)
    {
        float fac[4][4] = {};
        {
            float acc[4][4] = {};
            gemm_acc<128, 4>(acc, sB, ffn2_w1, 256, 0, 0, o04, pl4);
            const float4 b4 = *reinterpret_cast<const float4*>(ffn2_b1 + o04);
            const float bs[4] = {b4.x, b4.y, b4.z, b4.w};
#pragma unroll
            for (int j = 0; j < 4; ++j)
                st4(sA, o04 + j, pl4, make_float4(geluf_(acc[0][j] + bs[j]), geluf_(acc[1][j] + bs[j]),
                                                  geluf_(acc[2][j] + bs[j]), geluf_(acc[3][j] + bs[j])));
        }
        __syncthreads();
        gemm_acc<128, 4>(fac, sA, ffn2_w2, 128, 0, 0, o04, pl4);
        __syncthreads();
        {
            float acc[4][4] = {};
            gemm_acc<128, 4>(acc, sB, ffn2_w1, 256, 128, 0, o04, pl4);
            const float4 b4 = *reinterpret_cast<const float4*>(ffn2_b1 + 128 + o04);
            const float bs[4] = {b4.x, b4.y, b4.z, b4.w};
#pragma unroll
            for (int j = 0; j < 4; ++j)
                st4(sA, o04 + j, pl4, make_float4(geluf_(acc[0][j] + bs[j]), geluf_(acc[1][j] + bs[j]),
                                                  geluf_(acc[2][j] + bs[j]), geluf_(acc[3][j] + bs[j])));
        }
        __syncthreads();
        gemm_acc<128, 4>(fac, sA, ffn2_w2, 128, 0, 128, o04, pl4);
        {
            const float4 b4 = *reinterpret_cast<const float4*>(ffn2_b2 + o04);
            const float bs[4] = {b4.x, b4.y, b4.z, b4.w};
#pragma unroll
            for (int j = 0; j < 4; ++j)
                st4(sB, o04 + j, pl4, make_float4(fac[0][j] + bs[j], fac[1][j] + bs[j],
                                                  fac[2][j] + bs[j], fac[3][j] + bs[j]));
        }
    }
    __syncthreads();

    // ---------- sample f1w -> A
    sample128(feat1_s8, 48 * 64, 64, 2, sA);
    __syncthreads();

    // ---------- head layer 1 partials from f1w (rows 128..255) + scal (rows 256..259)
    float pa1[4][4] = {};
    float pa2[4][4] = {};
    gemm_acc<128, 4>(pa1, sA, hw1, 256, 0, 128, o04, pl4);
    gemm_acc<128, 4>(pa2, sA, hw1, 256, 128, 128, o04, pl4);
#pragma unroll
    for (int jj = 0; jj < 4; ++jj) {
        const float4 sv = *reinterpret_cast<const float4*>(sScal + jj * 32 + pl4);
        const float svk[4] = {sv.x, sv.y, sv.z, sv.w};
        const float4 wa = *reinterpret_cast<const float4*>(hw1 + (size_t)(256 + jj) * 256 + o04);
        const float4 wb = *reinterpret_cast<const float4*>(hw1 + (size_t)(256 + jj) * 256 + 128 + o04);
        const float wva[4] = {wa.x, wa.y, wa.z, wa.w};
        const float wvb[4] = {wb.x, wb.y, wb.z, wb.w};
#pragma unroll
        for (int j = 0; j < 4; ++j)
#pragma unroll
            for (int k = 0; k < 4; ++k) {
                pa1[k][j] = fmaf(svk[k], wva[j], pa1[k][j]);
                pa2[k][j] = fmaf(svk[k], wvb[j], pa2[k][j]);
            }
    }
    __syncthreads();   // A (f1w) fully consumed

    // ---------- head layer 1 half 1 + hw2 half 1
    float a2[4][4] = {};
    {
        gemm_acc<128, 4>(pa1, sB, hw1, 256, 0, 0, o04, pl4);
        const float4 b4 = *reinterpret_cast<const float4*>(hb1 + o04);
        const float bs[4] = {b4.x, b4.y, b4.z, b4.w};
#pragma unroll
        for (int j = 0; j < 4; ++j)
            st4(sA, o04 + j, pl4, make_float4(fmaxf(pa1[0][j] + bs[j], 0.0f), fmaxf(pa1[1][j] + bs[j], 0.0f),
                                              fmaxf(pa1[2][j] + bs[j], 0.0f), fmaxf(pa1[3][j] + bs[j], 0.0f)));
    }
    __syncthreads();
    gemm_acc<128, 4>(a2, sA, hw2, 128, 0, 0, o04, pl4);
    __syncthreads();
    // ---------- head layer 1 half 2 + hw2 half 2
    {
        gemm_acc<128, 4>(pa2, sB, hw1, 256, 128, 0, o04, pl4);
        const float4 b4 = *reinterpret_cast<const float4*>(hb1 + 128 + o04);
        const float bs[4] = {b4.x, b4.y, b4.z, b4.w};
#pragma unroll
        for (int j = 0; j < 4; ++j)
            st4(sA, o04 + j, pl4, make_float4(fmaxf(pa2[0][j] + bs[j], 0.0f), fmaxf(pa2[1][j] + bs[j], 0.0f),
                                              fmaxf(pa2[2][j] + bs[j], 0.0f), fmaxf(pa2[3][j] + bs[j], 0.0f)));
    }
    __syncthreads();
    gemm_acc<128, 4>(a2, sA, hw2, 128, 0, 128, o04, pl4);
    {
        const float4 b4 = *reinterpret_cast<const float4*>(hb2 + o04);
        const float bs[4] = {b4.x, b4.y, b4.z, b4.w};
#pragma unroll
        for (int j = 0; j < 4; ++j)
            st4(sB, o04 + j, pl4, make_float4(fmaxf(a2[0][j] + bs[j], 0.0f), fmaxf(a2[1][j] + bs[j], 0.0f),
                                              fmaxf(a2[2][j] + bs[j], 0.0f), fmaxf(a2[3][j] + bs[j], 0.0f)));
    }
    __syncthreads();

    // ---------- hw3 (128 -> 64 relu): B -> A rows 0..63
    {
        float acc[4][2] = {};
        const int o02 = ol * 2;
        gemm_acc<128, 2>(acc, sB, hw3, 64, 0, 0, o02, pl4);
        const float2 b2 = *reinterpret_cast<const float2*>(hb3 + o02);
        const float bs[2] = {b2.x, b2.y};
#pragma unroll
        for (int j = 0; j < 2; ++j)
            st4(sA, o02 + j, pl4, make_float4(fmaxf(acc[0][j] + bs[j], 0.0f), fmaxf(acc[1][j] + bs[j], 0.0f),
                                              fmaxf(acc[2][j] + bs[j], 0.0f), fmaxf(acc[3][j] + bs[j], 0.0f)));
    }
    __syncthreads();

    // ---------- hw4 (64 -> 2), flow = coarse_px + delta * [512, 384]
    if (t < 64) {
        const int pp = t >> 1;
        const int j = t & 1;
        float d = hb4[j];
#pragma unroll 8
        for (int i = 0; i < 64; ++i)
            d = fmaf(sA[i * STRIDE + ((pp & 3) | ((pp & ~3) ^ swzb(i)))], hw4[i * 2 + j], d);
        const int qq = blockIdx.x * NPTS + pp;
        const int bb = qq / 196608;
        const int rr = qq - bb * 196608;
        const int gyy = rr >> 9;
        const int gxx = rr & 511;
        float flow = sCps[j * 32 + pp] + d * (j == 0 ? 512.0f : 384.0f);
        out[(((size_t)bb * 2 + j) * 384 + gyy) * 512 + gxx] = flow;
    }
}

extern "C" void kernel_launch(void* const* d_in, const int* in_sizes, int n_in,
                              void* d_out, int out_size, void* d_ws, size_t ws_size,
                              hipStream_t stream) {
    const float* feat_s8 = (const float*)d_in[1];
    const float* feat1_s8 = (const float*)d_in[2];
    const float* feat_s16 = (const float*)d_in[3];
    const float* ctx_s8 = (const float*)d_in[4];
    const float* coarse_flow = (const float*)d_in[5];
    const float* ctx_w = (const float*)d_in[6];
    const float* ctx_b = (const float*)d_in[7];
    const float* gate1 = (const float*)d_in[8];
    const float* ffn1_w1 = (const float*)d_in[9];
    const float* ffn1_b1 = (const float*)d_in[10];
    const float* ffn1_w2 = (const float*)d_in[11];
    const float* ffn1_b2 = (const float*)d_in[12];
    const float* s8_w = (const float*)d_in[13];
    const float* s8_b = (const float*)d_in[14];
    const float* gate2 = (const float*)d_in[15];
    const float* ffn2_w1 = (const float*)d_in[16];
    const float* ffn2_b1 = (const float*)d_in[17];
    const float* ffn2_w2 = (const float*)d_in[18];
    const float* ffn2_b2 = (const float*)d_in[19];
    const float* hw1 = (const float*)d_in[20];
    const float* hb1 = (const float*)d_in[21];
    const float* hw2 = (const float*)d_in[22];
    const float* hb2 = (const float*)d_in[23];
    const float* hw3 = (const float*)d_in[24];
    const float* hb3 = (const float*)d_in[25];
    const float* hw4 = (const float*)d_in[26];
    const float* hb4 = (const float*)d_in[27];
    float* out = (float*)d_out;

    ifd_kernel<<<dim3(NBLOCKS), dim3(256), 0, stream>>>(
        feat_s8, feat1_s8, feat_s16, ctx_s8, coarse_flow,
        ctx_w, ctx_b, gate1, ffn1_w1, ffn1_b1, ffn1_w2, ffn1_b2,
        s8_w, s8_b, gate2, ffn2_w1, ffn2_b1, ffn2_w2, ffn2_b2,
        hw1, hb1, hw2, hb2, hw3, hb3, hw4, hb4, out);
}

// Round 3
// 1016.250 us; speedup vs baseline: 4.1962x; 3.4525x over previous
//
#include <hip/hip_runtime.h>
#include <math.h>

// ImplicitFlowDecoder round 3: f16 MFMA megakernel.
// - prepack kernel: fp32 weights -> f16 MFMA A-operand fragments in d_ws (512KB).
// - main kernel: 128 points/block, 256 threads (4 waves, 32 pts/wave).
//   Swapped-operand MFMA: D^T = mfma(Wfrag, ActFrag) so each lane holds 4 consecutive
//   CHANNELS of one point -> b64 epilogue stores, b64 residual loads.
//   Activations: 2x 128x128 f16 LDS buffers, swizzle ch ^ ((pt&15)<<3).
//   GEMM chain is wave-private in the point dimension -> barriers only around sampling.

typedef _Float16 half8 __attribute__((ext_vector_type(8)));
typedef _Float16 half4v __attribute__((ext_vector_type(4)));
typedef _Float16 half2v __attribute__((ext_vector_type(2)));
typedef float floatx4 __attribute__((ext_vector_type(4)));

#define NPOINTS_TOTAL (2 * 384 * 512)
#define PPB 128                       // points per block
#define NBLOCKS (NPOINTS_TOTAL / PPB) // 3072
#define PTS_PER_IMG 196608

// d_ws half-element offsets for prepacked weights
#define WS_CTX   0            // 64x128   (16KB)
#define WS_F1W1  8192         // 128x256  (64KB)
#define WS_F1W2  40960        // 256x128  (64KB)
#define WS_S8    73728        // 128x128  (32KB)
#define WS_F2W1  90112        // 128x256  (64KB)
#define WS_F2W2  122880       // 256x128  (64KB)
#define WS_HW1   155648       // 256x256  (128KB)
#define WS_HW2   221184       // 256x128  (64KB)
#define WS_HW3   253952       // 128x64   (16KB)
// total 262144 halves = 512KB

__device__ __forceinline__ float sigmoidf_(float x) { return 1.0f / (1.0f + expf(-x)); }
__device__ __forceinline__ float geluf_(float x) {
    return 0.5f * x * (1.0f + erff(x * 0.70710678118654752f));
}
__device__ __forceinline__ int swz(int pt) { return (pt & 15) << 3; }

// ---------------- prepack: W[K][N] fp32 -> f16 fragments -------------------
// tile (ks, ct): lane l holds W[ks*32 + (l>>4)*8 + j][ct*16 + (l&15)], j=0..7
__global__ void prepack_kernel(const float* __restrict__ ctx_w, const float* __restrict__ f1w1,
                               const float* __restrict__ f1w2, const float* __restrict__ s8w,
                               const float* __restrict__ f2w1, const float* __restrict__ f2w2,
                               const float* __restrict__ hw1, const float* __restrict__ hw2,
                               const float* __restrict__ hw3, _Float16* __restrict__ ws) {
    const int bid = blockIdx.x;
    const int lane = threadIdx.x;
    const float* src; int N, CT, start; size_t ofsH;
    if (bid < 16)       { src = ctx_w; N = 128; CT = 8;  start = 0;   ofsH = WS_CTX; }
    else if (bid < 80)  { src = f1w1;  N = 256; CT = 16; start = 16;  ofsH = WS_F1W1; }
    else if (bid < 144) { src = f1w2;  N = 128; CT = 8;  start = 80;  ofsH = WS_F1W2; }
    else if (bid < 176) { src = s8w;   N = 128; CT = 8;  start = 144; ofsH = WS_S8; }
    else if (bid < 240) { src = f2w1;  N = 256; CT = 16; start = 176; ofsH = WS_F2W1; }
    else if (bid < 304) { src = f2w2;  N = 128; CT = 8;  start = 240; ofsH = WS_F2W2; }
    else if (bid < 432) { src = hw1;   N = 256; CT = 16; start = 304; ofsH = WS_HW1; }
    else if (bid < 496) { src = hw2;   N = 128; CT = 8;  start = 432; ofsH = WS_HW2; }
    else                { src = hw3;   N = 64;  CT = 4;  start = 496; ofsH = WS_HW3; }
    const int ti = bid - start;
    const int ks = ti / CT, ct = ti % CT;
    const int m = lane & 15, g = lane >> 4;
    const int kb = ks * 32 + g * 8;
    const int n = ct * 16 + m;
    half8 v;
#pragma unroll
    for (int j = 0; j < 8; ++j) v[j] = (_Float16)src[(size_t)(kb + j) * N + n];
    *reinterpret_cast<half8*>(ws + ofsH + (size_t)ti * 512 + lane * 8) = v;
}

// ---------------- GEMM core ------------------------------------------------
// acc[ct][pr] (ch-tile ct, pt-rep pr) += W^T x Act^T over KS k-steps.
// wp: prepacked layer base; cts: ch-tiles in prepack layout; ks0/ct0: tile offsets.
template <int KS, int CT>
__device__ __forceinline__ void gemmT(floatx4 (&acc)[CT][2], const _Float16* __restrict__ wp,
                                      int cts, int ks0, int ct0,
                                      const _Float16* sact, int ptb, int lane) {
    const int m = lane & 15, g = lane >> 4;
    const int pt0 = ptb + m, pt1 = pt0 + 16;
    const int s0 = swz(pt0), s1 = swz(pt1);
    const _Float16* wbase = wp + ((size_t)(ks0 * cts + ct0) << 9) + lane * 8;
#pragma unroll
    for (int ks = 0; ks < KS; ++ks) {
        const int k0 = ks * 32 + g * 8;
        half8 a0 = *reinterpret_cast<const half8*>(sact + pt0 * 128 + (k0 ^ s0));
        half8 a1 = *reinterpret_cast<const half8*>(sact + pt1 * 128 + (k0 ^ s1));
        const _Float16* wk = wbase + ((size_t)(ks * cts) << 9);
#pragma unroll
        for (int ct = 0; ct < CT; ++ct) {
            half8 w = *reinterpret_cast<const half8*>(wk + ((size_t)ct << 9));
            acc[ct][0] = __builtin_amdgcn_mfma_f32_16x16x32_f16(w, a0, acc[ct][0], 0, 0, 0);
            acc[ct][1] = __builtin_amdgcn_mfma_f32_16x16x32_f16(w, a1, acc[ct][1], 0, 0, 0);
        }
    }
}

__device__ __forceinline__ void storeH4(_Float16* dst, int pt, int ch0,
                                        float o0, float o1, float o2, float o3) {
    half4v hv;
    hv[0] = (_Float16)o0; hv[1] = (_Float16)o1; hv[2] = (_Float16)o2; hv[3] = (_Float16)o3;
    *reinterpret_cast<half4v*>(dst + pt * 128 + (ch0 ^ swz(pt))) = hv;
}
__device__ __forceinline__ half4v loadH4(const _Float16* src, int pt, int ch0) {
    return *reinterpret_cast<const half4v*>(src + pt * 128 + (ch0 ^ swz(pt)));
}

// ---------------- main kernel ----------------------------------------------
__global__ void __launch_bounds__(256, 2)
ifd_mfma(const float* __restrict__ feat_s8, const float* __restrict__ feat1_s8,
         const float* __restrict__ feat_s16, const float* __restrict__ ctx_s8,
         const float* __restrict__ coarse_flow,
         const float* __restrict__ ctx_b, const float* __restrict__ gate1,
         const float* __restrict__ ffn1_b1, const float* __restrict__ ffn1_b2,
         const float* __restrict__ s8_b, const float* __restrict__ gate2,
         const float* __restrict__ ffn2_b1, const float* __restrict__ ffn2_b2,
         const float* __restrict__ hw1, const float* __restrict__ hb1,
         const float* __restrict__ hb2, const float* __restrict__ hb3,
         const float* __restrict__ hw4, const float* __restrict__ hb4,
         const _Float16* __restrict__ wsp, float* __restrict__ out) {
    __shared__ __align__(16) _Float16 bufA[128 * 128];
    __shared__ __align__(16) _Float16 bufB[128 * 128];
    __shared__ float sScal[4 * 128];   // cn_x, cn_y, cfn_x, cfn_y
    __shared__ float sCps[2 * 128];    // coarse flow in full-res px
    __shared__ int   sIdx[3 * 4 * 128];
    __shared__ float sWgt[3 * 2 * 128];

    const int t = threadIdx.x;
    const int lane = t & 63, wid = t >> 6;
    const int m = lane & 15, g = lane >> 4;
    const int ptb = wid * 32;
    const int b = blockIdx.x / 1536;          // image index
    const int qbase = blockIdx.x * PPB;
    const float CHI = 1.0f - 1e-6f;

    // ---------- coords + coarse-flow sample + warp (threads 0..127, 1 point each)
    if (t < 128) {
        const int p = t;
        const int rem = qbase + p - b * PTS_PER_IMG;
        const int gy = rem >> 9, gx = rem & 511;
        float cnx = fminf(fmaxf(2.0f * ((float)gx + 0.5f) / 512.0f - 1.0f, -CHI), CHI);
        float cny = fminf(fmaxf(2.0f * ((float)gy + 0.5f) / 384.0f - 1.0f, -CHI), CHI);

        auto mkc = [](float cn, float Sf, int Smax, int& i0, int& i1, float& w) {
            float x = fminf(fmaxf(((cn + 1.0f) * Sf - 1.0f) * 0.5f, 0.0f), Sf - 1.0f);
            float xf = floorf(x);
            w = x - xf;
            i0 = (int)xf;
            i1 = (i0 + 1 > Smax) ? Smax : i0 + 1;
        };
        auto storeSet = [&](int s, int x0, int x1, int y0, int y1, float wx, float wy) {
            sIdx[s * 512 + 0 * 128 + p] = x0; sIdx[s * 512 + 1 * 128 + p] = x1;
            sIdx[s * 512 + 2 * 128 + p] = y0; sIdx[s * 512 + 3 * 128 + p] = y1;
            sWgt[s * 256 + p] = wx; sWgt[s * 256 + 128 + p] = wy;
        };

        int x0, x1, y0, y1; float wx, wy;
        mkc(cnx, 64.0f, 63, x0, x1, wx);
        mkc(cny, 48.0f, 47, y0, y1, wy);
        storeSet(0, x0, x1, y0, y1, wx, wy);

        int X0, X1, Y0, Y1; float WX, WY;
        mkc(cnx, 32.0f, 31, X0, X1, WX);
        mkc(cny, 24.0f, 23, Y0, Y1, WY);
        storeSet(1, X0, X1, Y0, Y1, WX, WY);

        const float w00 = (1.0f - wx) * (1.0f - wy), w01 = wx * (1.0f - wy);
        const float w10 = (1.0f - wx) * wy, w11 = wx * wy;
        const int i00 = y0 * 64 + x0, i01 = y0 * 64 + x1, i10 = y1 * 64 + x0, i11 = y1 * 64 + x1;
        const float* cf = coarse_flow + (size_t)b * 6144;
        float c0 = (cf[i00] * w00 + cf[i01] * w01 + cf[i10] * w10 + cf[i11] * w11) * 8.0f;
        const float* cf1 = cf + 3072;
        float c1 = (cf1[i00] * w00 + cf1[i01] * w01 + cf1[i10] * w10 + cf1[i11] * w11) * 8.0f;
        sCps[p] = c0; sCps[128 + p] = c1;
        sScal[p] = cnx; sScal[128 + p] = cny;
        sScal[256 + p] = c0 / 512.0f; sScal[384 + p] = c1 / 384.0f;

        float wxn = fminf(fmaxf(cnx + 2.0f * c0 / 512.0f, -CHI), CHI);
        float wyn = fminf(fmaxf(cny + 2.0f * c1 / 384.0f, -CHI), CHI);
        int u0, u1, v0, v1; float uw, vw;
        mkc(wxn, 64.0f, 63, u0, u1, uw);
        mkc(wyn, 48.0f, 47, v0, v1, vw);
        storeSet(2, u0, u1, v0, v1, uw, vw);
    }
    __syncthreads();   // B1

    // ---------- sampling helper: thread t samples point (t&127), channel-half (t>>7)
    auto sampleMap = [&](const float* __restrict__ mapB, int C, int HW, int Wd, int set,
                         _Float16* dst) {
        const int pt = t & 127, hs = t >> 7;
        const int x0 = sIdx[set * 512 + pt], x1 = sIdx[set * 512 + 128 + pt];
        const int y0 = sIdx[set * 512 + 256 + pt], y1 = sIdx[set * 512 + 384 + pt];
        const float wx = sWgt[set * 256 + pt], wy = sWgt[set * 256 + 128 + pt];
        const float w00 = (1.0f - wx) * (1.0f - wy), w01 = wx * (1.0f - wy);
        const float w10 = (1.0f - wx) * wy, w11 = wx * wy;
        const int i00 = y0 * Wd + x0, i01 = y0 * Wd + x1, i10 = y1 * Wd + x0, i11 = y1 * Wd + x1;
        const int np = C >> 2;                 // channel-pairs per thread
#pragma unroll 4
        for (int i = 0; i < np; ++i) {
            const int c0 = hs * (C >> 1) + 2 * i;
            const float* p0 = mapB + (size_t)c0 * HW;
            const float* p1 = p0 + HW;
            float v0 = p0[i00] * w00 + p0[i01] * w01 + p0[i10] * w10 + p0[i11] * w11;
            float v1 = p1[i00] * w00 + p1[i01] * w01 + p1[i10] * w10 + p1[i11] * w11;
            half2v hv; hv[0] = (_Float16)v0; hv[1] = (_Float16)v1;
            *reinterpret_cast<half2v*>(dst + pt * 128 + (c0 ^ swz(pt))) = hv;
        }
    };

    // ---------- sample f8 -> bufA, fctx -> bufB[:,0:64]
    sampleMap(feat_s8 + (size_t)b * 128 * 3072, 128, 3072, 64, 0, bufA);
    sampleMap(ctx_s8 + (size_t)b * 64 * 3072, 64, 3072, 64, 0, bufB);
    __syncthreads();   // B2

    // ---------- ctx: h2 = f8 + sig(g1)*(fctx @ ctx_w + ctx_b)   (bufB -> bufA)
    {
        floatx4 acc[8][2];
#pragma unroll
        for (int c = 0; c < 8; ++c) { acc[c][0] = (floatx4)0.0f; acc[c][1] = (floatx4)0.0f; }
        gemmT<2, 8>(acc, wsp + WS_CTX, 8, 0, 0, bufB, ptb, lane);
#pragma unroll
        for (int ct = 0; ct < 8; ++ct) {
            const int ch0 = ct * 16 + g * 4;
            const float4 bb = *reinterpret_cast<const float4*>(ctx_b + ch0);
            const float4 gg = *reinterpret_cast<const float4*>(gate1 + ch0);
            const float g0 = sigmoidf_(gg.x), g1v = sigmoidf_(gg.y),
                        g2v = sigmoidf_(gg.z), g3 = sigmoidf_(gg.w);
#pragma unroll
            for (int pr = 0; pr < 2; ++pr) {
                const int pt = ptb + pr * 16 + m;
                half4v rv = loadH4(bufA, pt, ch0);
                floatx4 v = acc[ct][pr];
                storeH4(bufA, pt, ch0,
                        (float)rv[0] + g0 * (v[0] + bb.x), (float)rv[1] + g1v * (v[1] + bb.y),
                        (float)rv[2] + g2v * (v[2] + bb.z), (float)rv[3] + g3 * (v[3] + bb.w));
            }
        }
    }

    // ---------- ffn1: bufA -> bufA (scratch bufB)
    {
        floatx4 acc2[8][2];
#pragma unroll
        for (int c = 0; c < 8; ++c) { acc2[c][0] = (floatx4)0.0f; acc2[c][1] = (floatx4)0.0f; }
#pragma unroll
        for (int half = 0; half < 2; ++half) {
            floatx4 au[8][2];
#pragma unroll
            for (int c = 0; c < 8; ++c) { au[c][0] = (floatx4)0.0f; au[c][1] = (floatx4)0.0f; }
            gemmT<4, 8>(au, wsp + WS_F1W1, 16, 0, half * 8, bufA, ptb, lane);
#pragma unroll
            for (int ct = 0; ct < 8; ++ct) {
                const int ch0 = ct * 16 + g * 4;
                const float4 bb = *reinterpret_cast<const float4*>(ffn1_b1 + half * 128 + ch0);
#pragma unroll
                for (int pr = 0; pr < 2; ++pr) {
                    const int pt = ptb + pr * 16 + m;
                    floatx4 v = au[ct][pr];
                    storeH4(bufB, pt, ch0, geluf_(v[0] + bb.x), geluf_(v[1] + bb.y),
                            geluf_(v[2] + bb.z), geluf_(v[3] + bb.w));
                }
            }
            gemmT<4, 8>(acc2, wsp + WS_F1W2, 8, half * 4, 0, bufB, ptb, lane);
        }
#pragma unroll
        for (int ct = 0; ct < 8; ++ct) {
            const int ch0 = ct * 16 + g * 4;
            const float4 bb = *reinterpret_cast<const float4*>(ffn1_b2 + ch0);
#pragma unroll
            for (int pr = 0; pr < 2; ++pr) {
                const int pt = ptb + pr * 16 + m;
                floatx4 v = acc2[ct][pr];
                storeH4(bufA, pt, ch0, v[0] + bb.x, v[1] + bb.y, v[2] + bb.z, v[3] + bb.w);
            }
        }
    }
    __syncthreads();   // B3 (bufB about to be overwritten cross-wave)

    // ---------- sample f16 -> bufB
    sampleMap(feat_s16 + (size_t)b * 128 * 768, 128, 768, 32, 1, bufB);
    __syncthreads();   // B4

    // ---------- s8: h3 = f16 + sig(g2)*(h2' @ s8_w + s8_b)   (bufA -> bufB)
    {
        floatx4 acc[8][2];
#pragma unroll
        for (int c = 0; c < 8; ++c) { acc[c][0] = (floatx4)0.0f; acc[c][1] = (floatx4)0.0f; }
        gemmT<4, 8>(acc, wsp + WS_S8, 8, 0, 0, bufA, ptb, lane);
#pragma unroll
        for (int ct = 0; ct < 8; ++ct) {
            const int ch0 = ct * 16 + g * 4;
            const float4 bb = *reinterpret_cast<const float4*>(s8_b + ch0);
            const float4 gg = *reinterpret_cast<const float4*>(gate2 + ch0);
            const float g0 = sigmoidf_(gg.x), g1v = sigmoidf_(gg.y),
                        g2v = sigmoidf_(gg.z), g3 = sigmoidf_(gg.w);
#pragma unroll
            for (int pr = 0; pr < 2; ++pr) {
                const int pt = ptb + pr * 16 + m;
                half4v rv = loadH4(bufB, pt, ch0);
                floatx4 v = acc[ct][pr];
                storeH4(bufB, pt, ch0,
                        (float)rv[0] + g0 * (v[0] + bb.x), (float)rv[1] + g1v * (v[1] + bb.y),
                        (float)rv[2] + g2v * (v[2] + bb.z), (float)rv[3] + g3 * (v[3] + bb.w));
            }
        }
    }

    // ---------- ffn2: bufB -> bufB (scratch bufA)
    {
        floatx4 acc3[8][2];
#pragma unroll
        for (int c = 0; c < 8; ++c) { acc3[c][0] = (floatx4)0.0f; acc3[c][1] = (floatx4)0.0f; }
#pragma unroll
        for (int half = 0; half < 2; ++half) {
            floatx4 au[8][2];
#pragma unroll
            for (int c = 0; c < 8; ++c) { au[c][0] = (floatx4)0.0f; au[c][1] = (floatx4)0.0f; }
            gemmT<4, 8>(au, wsp + WS_F2W1, 16, 0, half * 8, bufB, ptb, lane);
#pragma unroll
            for (int ct = 0; ct < 8; ++ct) {
                const int ch0 = ct * 16 + g * 4;
                const float4 bb = *reinterpret_cast<const float4*>(ffn2_b1 + half * 128 + ch0);
#pragma unroll
                for (int pr = 0; pr < 2; ++pr) {
                    const int pt = ptb + pr * 16 + m;
                    floatx4 v = au[ct][pr];
                    storeH4(bufA, pt, ch0, geluf_(v[0] + bb.x), geluf_(v[1] + bb.y),
                            geluf_(v[2] + bb.z), geluf_(v[3] + bb.w));
                }
            }
            gemmT<4, 8>(acc3, wsp + WS_F2W2, 8, half * 4, 0, bufA, ptb, lane);
        }
#pragma unroll
        for (int ct = 0; ct < 8; ++ct) {
            const int ch0 = ct * 16 + g * 4;
            const float4 bb = *reinterpret_cast<const float4*>(ffn2_b2 + ch0);
#pragma unroll
            for (int pr = 0; pr < 2; ++pr) {
                const int pt = ptb + pr * 16 + m;
                floatx4 v = acc3[ct][pr];
                storeH4(bufB, pt, ch0, v[0] + bb.x, v[1] + bb.y, v[2] + bb.z, v[3] + bb.w);
            }
        }
    }
    __syncthreads();   // B5 (bufA about to be overwritten cross-wave)

    // ---------- sample f1w -> bufA
    sampleMap(feat1_s8 + (size_t)b * 128 * 3072, 128, 3072, 64, 2, bufA);
    __syncthreads();   // B6

    // ---------- head1 (260->256 relu): fused(bufB) rows0..127, f1w(bufA) rows128..255, scal 256..259
    {
        floatx4 acc4[16][2];
#pragma unroll
        for (int c = 0; c < 16; ++c) { acc4[c][0] = (floatx4)0.0f; acc4[c][1] = (floatx4)0.0f; }
        gemmT<4, 16>(acc4, wsp + WS_HW1, 16, 0, 0, bufB, ptb, lane);
        gemmT<4, 16>(acc4, wsp + WS_HW1, 16, 4, 0, bufA, ptb, lane);
#pragma unroll
        for (int ct = 0; ct < 16; ++ct) {
            const int ch0 = ct * 16 + g * 4;
#pragma unroll
            for (int jj = 0; jj < 4; ++jj) {
                const float4 wj = *reinterpret_cast<const float4*>(hw1 + (size_t)(256 + jj) * 256 + ch0);
#pragma unroll
                for (int pr = 0; pr < 2; ++pr) {
                    const int pt = ptb + pr * 16 + m;
                    const float s = sScal[jj * 128 + pt];
                    floatx4 v = acc4[ct][pr];
                    v[0] = fmaf(wj.x, s, v[0]); v[1] = fmaf(wj.y, s, v[1]);
                    v[2] = fmaf(wj.z, s, v[2]); v[3] = fmaf(wj.w, s, v[3]);
                    acc4[ct][pr] = v;
                }
            }
        }
#pragma unroll
        for (int ct = 0; ct < 16; ++ct) {
            const int ch0 = ct * 16 + g * 4;
            const float4 bb = *reinterpret_cast<const float4*>(hb1 + ch0);
            _Float16* dst = (ct < 8) ? bufA : bufB;
            const int ch0w = (ct & 7) * 16 + g * 4;
#pragma unroll
            for (int pr = 0; pr < 2; ++pr) {
                const int pt = ptb + pr * 16 + m;
                floatx4 v = acc4[ct][pr];
                storeH4(dst, pt, ch0w, fmaxf(v[0] + bb.x, 0.0f), fmaxf(v[1] + bb.y, 0.0f),
                        fmaxf(v[2] + bb.z, 0.0f), fmaxf(v[3] + bb.w, 0.0f));
            }
        }
    }

    // ---------- head2 (256->128 relu): rows0..127=bufA, rows128..255=bufB -> bufA
    {
        floatx4 acc5[8][2];
#pragma unroll
        for (int c = 0; c < 8; ++c) { acc5[c][0] = (floatx4)0.0f; acc5[c][1] = (floatx4)0.0f; }
        gemmT<4, 8>(acc5, wsp + WS_HW2, 8, 0, 0, bufA, ptb, lane);
        gemmT<4, 8>(acc5, wsp + WS_HW2, 8, 4, 0, bufB, ptb, lane);
#pragma unroll
        for (int ct = 0; ct < 8; ++ct) {
            const int ch0 = ct * 16 + g * 4;
            const float4 bb = *reinterpret_cast<const float4*>(hb2 + ch0);
#pragma unroll
            for (int pr = 0; pr < 2; ++pr) {
                const int pt = ptb + pr * 16 + m;
                floatx4 v = acc5[ct][pr];
                storeH4(bufA, pt, ch0, fmaxf(v[0] + bb.x, 0.0f), fmaxf(v[1] + bb.y, 0.0f),
                        fmaxf(v[2] + bb.z, 0.0f), fmaxf(v[3] + bb.w, 0.0f));
            }
        }
    }

    // ---------- head3 (128->64 relu): bufA -> bufB[:,0:64]
    {
        floatx4 acc6[4][2];
#pragma unroll
        for (int c = 0; c < 4; ++c) { acc6[c][0] = (floatx4)0.0f; acc6[c][1] = (floatx4)0.0f; }
        gemmT<4, 4>(acc6, wsp + WS_HW3, 4, 0, 0, bufA, ptb, lane);
#pragma unroll
        for (int ct = 0; ct < 4; ++ct) {
            const int ch0 = ct * 16 + g * 4;
            const float4 bb = *reinterpret_cast<const float4*>(hb3 + ch0);
#pragma unroll
            for (int pr = 0; pr < 2; ++pr) {
                const int pt = ptb + pr * 16 + m;
                floatx4 v = acc6[ct][pr];
                storeH4(bufB, pt, ch0, fmaxf(v[0] + bb.x, 0.0f), fmaxf(v[1] + bb.y, 0.0f),
                        fmaxf(v[2] + bb.z, 0.0f), fmaxf(v[3] + bb.w, 0.0f));
            }
        }
    }
    __syncthreads();   // B7 (head4 reads bufB cross-wave)

    // ---------- head4 (64->2) fp32 + flow combine + store
    {
        const int pp = t >> 1, j = t & 1;
        float d = hb4[j];
#pragma unroll
        for (int i8 = 0; i8 < 8; ++i8) {
            const int c0 = i8 * 8;
            half8 hv = *reinterpret_cast<const half8*>(bufB + pp * 128 + (c0 ^ swz(pp)));
#pragma unroll
            for (int j2 = 0; j2 < 8; ++j2)
                d = fmaf((float)hv[j2], hw4[(c0 + j2) * 2 + j], d);
        }
        const int q = qbase + pp;
        const int rem = q - b * PTS_PER_IMG;
        const int gy = rem >> 9, gx = rem & 511;
        const float flow = sCps[j * 128 + pp] + d * (j == 0 ? 512.0f : 384.0f);
        out[(((size_t)b * 2 + j) * 384 + gy) * 512 + gx] = flow;
    }
}

extern "C" void kernel_launch(void* const* d_in, const int* in_sizes, int n_in,
                              void* d_out, int out_size, void* d_ws, size_t ws_size,
                              hipStream_t stream) {
    const float* feat_s8 = (const float*)d_in[1];
    const float* feat1_s8 = (const float*)d_in[2];
    const float* feat_s16 = (const float*)d_in[3];
    const float* ctx_s8 = (const float*)d_in[4];
    const float* coarse_flow = (const float*)d_in[5];
    const float* ctx_w = (const float*)d_in[6];
    const float* ctx_b = (const float*)d_in[7];
    const float* gate1 = (const float*)d_in[8];
    const float* ffn1_w1 = (const float*)d_in[9];
    const float* ffn1_b1 = (const float*)d_in[10];
    const float* ffn1_w2 = (const float*)d_in[11];
    const float* ffn1_b2 = (const float*)d_in[12];
    const float* s8_w = (const float*)d_in[13];
    const float* s8_b = (const float*)d_in[14];
    const float* gate2 = (const float*)d_in[15];
    const float* ffn2_w1 = (const float*)d_in[16];
    const float* ffn2_b1 = (const float*)d_in[17];
    const float* ffn2_w2 = (const float*)d_in[18];
    const float* ffn2_b2 = (const float*)d_in[19];
    const float* hw1 = (const float*)d_in[20];
    const float* hb1 = (const float*)d_in[21];
    const float* hw2 = (const float*)d_in[22];
    const float* hb2 = (const float*)d_in[23];
    const float* hw3 = (const float*)d_in[24];
    const float* hb3 = (const float*)d_in[25];
    const float* hw4 = (const float*)d_in[26];
    const float* hb4 = (const float*)d_in[27];
    float* out = (float*)d_out;
    _Float16* wsp = (_Float16*)d_ws;

    prepack_kernel<<<dim3(512), dim3(64), 0, stream>>>(
        ctx_w, ffn1_w1, ffn1_w2, s8_w, ffn2_w1, ffn2_w2, hw1, hw2, hw3, wsp);

    ifd_mfma<<<dim3(NBLOCKS), dim3(256), 0, stream>>>(
        feat_s8, feat1_s8, feat_s16, ctx_s8, coarse_flow,
        ctx_b, gate1, ffn1_b1, ffn1_b2, s8_b, gate2, ffn2_b1, ffn2_b2,
        hw1, hb1, hb2, hb3, hw4, hb4, wsp, out);
}

// Round 4
// 792.605 us; speedup vs baseline: 5.3803x; 1.2822x over previous
//
#include <hip/hip_runtime.h>
#include <math.h>

// ImplicitFlowDecoder round 4: f16 MFMA megakernel, spill-free live ranges.
// - prepack kernel: fp32 weights -> f16 MFMA A-operand fragments in d_ws (512KB).
// - main kernel: 128 points/block, 256 threads (4 waves, 32 pts/wave).
//   Swapped-operand MFMA: D^T = mfma(Wfrag, ActFrag); lane holds 4 consecutive
//   channels of one point -> b64 epilogues. Act buffers: 2x 128x128 f16 LDS,
//   swizzle ch ^ ((pt&15)<<3). GEMM chain wave-private in points.
// Round-4 changes (anti-spill):
//   * FFNs: gelu half0 -> scratch buf, half1 -> input buf (input dead); acc alone.
//   * head1: f1w kept as register B-fragments; two 8-tile halves.

typedef _Float16 half8 __attribute__((ext_vector_type(8)));
typedef _Float16 half4v __attribute__((ext_vector_type(4)));
typedef _Float16 half2v __attribute__((ext_vector_type(2)));
typedef float floatx4 __attribute__((ext_vector_type(4)));

#define NPOINTS_TOTAL (2 * 384 * 512)
#define PPB 128
#define NBLOCKS (NPOINTS_TOTAL / PPB)
#define PTS_PER_IMG 196608

#define WS_CTX   0
#define WS_F1W1  8192
#define WS_F1W2  40960
#define WS_S8    73728
#define WS_F2W1  90112
#define WS_F2W2  122880
#define WS_HW1   155648
#define WS_HW2   221184
#define WS_HW3   253952

__device__ __forceinline__ float sigmoidf_(float x) { return 1.0f / (1.0f + expf(-x)); }
__device__ __forceinline__ float geluf_(float x) {
    return 0.5f * x * (1.0f + erff(x * 0.70710678118654752f));
}
__device__ __forceinline__ int swz(int pt) { return (pt & 15) << 3; }

// ---------------- prepack: W[K][N] fp32 -> f16 fragments -------------------
__global__ void prepack_kernel(const float* __restrict__ ctx_w, const float* __restrict__ f1w1,
                               const float* __restrict__ f1w2, const float* __restrict__ s8w,
                               const float* __restrict__ f2w1, const float* __restrict__ f2w2,
                               const float* __restrict__ hw1, const float* __restrict__ hw2,
                               const float* __restrict__ hw3, _Float16* __restrict__ ws) {
    const int bid = blockIdx.x;
    const int lane = threadIdx.x;
    const float* src; int N, CT, start; size_t ofsH;
    if (bid < 16)       { src = ctx_w; N = 128; CT = 8;  start = 0;   ofsH = WS_CTX; }
    else if (bid < 80)  { src = f1w1;  N = 256; CT = 16; start = 16;  ofsH = WS_F1W1; }
    else if (bid < 144) { src = f1w2;  N = 128; CT = 8;  start = 80;  ofsH = WS_F1W2; }
    else if (bid < 176) { src = s8w;   N = 128; CT = 8;  start = 144; ofsH = WS_S8; }
    else if (bid < 240) { src = f2w1;  N = 256; CT = 16; start = 176; ofsH = WS_F2W1; }
    else if (bid < 304) { src = f2w2;  N = 128; CT = 8;  start = 240; ofsH = WS_F2W2; }
    else if (bid < 432) { src = hw1;   N = 256; CT = 16; start = 304; ofsH = WS_HW1; }
    else if (bid < 496) { src = hw2;   N = 128; CT = 8;  start = 432; ofsH = WS_HW2; }
    else                { src = hw3;   N = 64;  CT = 4;  start = 496; ofsH = WS_HW3; }
    const int ti = bid - start;
    const int ks = ti / CT, ct = ti % CT;
    const int m = lane & 15, g = lane >> 4;
    const int kb = ks * 32 + g * 8;
    const int n = ct * 16 + m;
    half8 v;
#pragma unroll
    for (int j = 0; j < 8; ++j) v[j] = (_Float16)src[(size_t)(kb + j) * N + n];
    *reinterpret_cast<half8*>(ws + ofsH + (size_t)ti * 512 + lane * 8) = v;
}

// ---------------- GEMM cores -----------------------------------------------
template <int KS, int CT>
__device__ __forceinline__ void gemmT(floatx4 (&acc)[CT][2], const _Float16* __restrict__ wp,
                                      int cts, int ks0, int ct0,
                                      const _Float16* sact, int ptb, int lane) {
    const int m = lane & 15, g = lane >> 4;
    const int pt0 = ptb + m, pt1 = pt0 + 16;
    const int s0 = swz(pt0), s1 = swz(pt1);
    const _Float16* wbase = wp + ((size_t)(ks0 * cts + ct0) << 9) + lane * 8;
#pragma unroll
    for (int ks = 0; ks < KS; ++ks) {
        const int k0 = ks * 32 + g * 8;
        half8 a0 = *reinterpret_cast<const half8*>(sact + pt0 * 128 + (k0 ^ s0));
        half8 a1 = *reinterpret_cast<const half8*>(sact + pt1 * 128 + (k0 ^ s1));
        const _Float16* wk = wbase + ((size_t)(ks * cts) << 9);
#pragma unroll
        for (int ct = 0; ct < CT; ++ct) {
            half8 w = *reinterpret_cast<const half8*>(wk + ((size_t)ct << 9));
            acc[ct][0] = __builtin_amdgcn_mfma_f32_16x16x32_f16(w, a0, acc[ct][0], 0, 0, 0);
            acc[ct][1] = __builtin_amdgcn_mfma_f32_16x16x32_f16(w, a1, acc[ct][1], 0, 0, 0);
        }
    }
}

// same but B-operand fragments come from registers
template <int KS, int CT>
__device__ __forceinline__ void gemmRegB(floatx4 (&acc)[CT][2], const _Float16* __restrict__ wp,
                                         int cts, int ks0, int ct0,
                                         const half8 (&fr)[KS][2], int lane) {
    const _Float16* wbase = wp + ((size_t)(ks0 * cts + ct0) << 9) + lane * 8;
#pragma unroll
    for (int ks = 0; ks < KS; ++ks) {
        const _Float16* wk = wbase + ((size_t)(ks * cts) << 9);
#pragma unroll
        for (int ct = 0; ct < CT; ++ct) {
            half8 w = *reinterpret_cast<const half8*>(wk + ((size_t)ct << 9));
            acc[ct][0] = __builtin_amdgcn_mfma_f32_16x16x32_f16(w, fr[ks][0], acc[ct][0], 0, 0, 0);
            acc[ct][1] = __builtin_amdgcn_mfma_f32_16x16x32_f16(w, fr[ks][1], acc[ct][1], 0, 0, 0);
        }
    }
}

__device__ __forceinline__ void loadFrags(half8 (&fr)[4][2], const _Float16* sact, int ptb, int lane) {
    const int m = lane & 15, g = lane >> 4;
    const int pt0 = ptb + m, pt1 = pt0 + 16;
    const int s0 = swz(pt0), s1 = swz(pt1);
#pragma unroll
    for (int ks = 0; ks < 4; ++ks) {
        const int k0 = ks * 32 + g * 8;
        fr[ks][0] = *reinterpret_cast<const half8*>(sact + pt0 * 128 + (k0 ^ s0));
        fr[ks][1] = *reinterpret_cast<const half8*>(sact + pt1 * 128 + (k0 ^ s1));
    }
}

__device__ __forceinline__ void storeH4(_Float16* dst, int pt, int ch0,
                                        float o0, float o1, float o2, float o3) {
    half4v hv;
    hv[0] = (_Float16)o0; hv[1] = (_Float16)o1; hv[2] = (_Float16)o2; hv[3] = (_Float16)o3;
    *reinterpret_cast<half4v*>(dst + pt * 128 + (ch0 ^ swz(pt))) = hv;
}
__device__ __forceinline__ half4v loadH4(const _Float16* src, int pt, int ch0) {
    return *reinterpret_cast<const half4v*>(src + pt * 128 + (ch0 ^ swz(pt)));
}

// ---------------- main kernel ----------------------------------------------
__global__ void __launch_bounds__(256, 2)
ifd_mfma(const float* __restrict__ feat_s8, const float* __restrict__ feat1_s8,
         const float* __restrict__ feat_s16, const float* __restrict__ ctx_s8,
         const float* __restrict__ coarse_flow,
         const float* __restrict__ ctx_b, const float* __restrict__ gate1,
         const float* __restrict__ ffn1_b1, const float* __restrict__ ffn1_b2,
         const float* __restrict__ s8_b, const float* __restrict__ gate2,
         const float* __restrict__ ffn2_b1, const float* __restrict__ ffn2_b2,
         const float* __restrict__ hw1, const float* __restrict__ hb1,
         const float* __restrict__ hb2, const float* __restrict__ hb3,
         const float* __restrict__ hw4, const float* __restrict__ hb4,
         const _Float16* __restrict__ wsp, float* __restrict__ out) {
    __shared__ __align__(16) _Float16 bufA[128 * 128];
    __shared__ __align__(16) _Float16 bufB[128 * 128];
    __shared__ float sScal[4 * 128];
    __shared__ float sCps[2 * 128];
    __shared__ int   sIdx[3 * 4 * 128];
    __shared__ float sWgt[3 * 2 * 128];

    const int t = threadIdx.x;
    const int lane = t & 63, wid = t >> 6;
    const int m = lane & 15, g = lane >> 4;
    const int ptb = wid * 32;
    const int b = blockIdx.x / 1536;
    const int qbase = blockIdx.x * PPB;
    const float CHI = 1.0f - 1e-6f;

    // ---------- coords + coarse-flow sample + warp (threads 0..127)
    if (t < 128) {
        const int p = t;
        const int rem = qbase + p - b * PTS_PER_IMG;
        const int gy = rem >> 9, gx = rem & 511;
        float cnx = fminf(fmaxf(2.0f * ((float)gx + 0.5f) / 512.0f - 1.0f, -CHI), CHI);
        float cny = fminf(fmaxf(2.0f * ((float)gy + 0.5f) / 384.0f - 1.0f, -CHI), CHI);

        auto mkc = [](float cn, float Sf, int Smax, int& i0, int& i1, float& w) {
            float x = fminf(fmaxf(((cn + 1.0f) * Sf - 1.0f) * 0.5f, 0.0f), Sf - 1.0f);
            float xf = floorf(x);
            w = x - xf;
            i0 = (int)xf;
            i1 = (i0 + 1 > Smax) ? Smax : i0 + 1;
        };
        auto storeSet = [&](int s, int x0, int x1, int y0, int y1, float wx, float wy) {
            sIdx[s * 512 + 0 * 128 + p] = x0; sIdx[s * 512 + 1 * 128 + p] = x1;
            sIdx[s * 512 + 2 * 128 + p] = y0; sIdx[s * 512 + 3 * 128 + p] = y1;
            sWgt[s * 256 + p] = wx; sWgt[s * 256 + 128 + p] = wy;
        };

        int x0, x1, y0, y1; float wx, wy;
        mkc(cnx, 64.0f, 63, x0, x1, wx);
        mkc(cny, 48.0f, 47, y0, y1, wy);
        storeSet(0, x0, x1, y0, y1, wx, wy);

        int X0, X1, Y0, Y1; float WX, WY;
        mkc(cnx, 32.0f, 31, X0, X1, WX);
        mkc(cny, 24.0f, 23, Y0, Y1, WY);
        storeSet(1, X0, X1, Y0, Y1, WX, WY);

        const float w00 = (1.0f - wx) * (1.0f - wy), w01 = wx * (1.0f - wy);
        const float w10 = (1.0f - wx) * wy, w11 = wx * wy;
        const int i00 = y0 * 64 + x0, i01 = y0 * 64 + x1, i10 = y1 * 64 + x0, i11 = y1 * 64 + x1;
        const float* cf = coarse_flow + (size_t)b * 6144;
        float c0 = (cf[i00] * w00 + cf[i01] * w01 + cf[i10] * w10 + cf[i11] * w11) * 8.0f;
        const float* cf1 = cf + 3072;
        float c1 = (cf1[i00] * w00 + cf1[i01] * w01 + cf1[i10] * w10 + cf1[i11] * w11) * 8.0f;
        sCps[p] = c0; sCps[128 + p] = c1;
        sScal[p] = cnx; sScal[128 + p] = cny;
        sScal[256 + p] = c0 / 512.0f; sScal[384 + p] = c1 / 384.0f;

        float wxn = fminf(fmaxf(cnx + 2.0f * c0 / 512.0f, -CHI), CHI);
        float wyn = fminf(fmaxf(cny + 2.0f * c1 / 384.0f, -CHI), CHI);
        int u0, u1, v0, v1; float uw, vw;
        mkc(wxn, 64.0f, 63, u0, u1, uw);
        mkc(wyn, 48.0f, 47, v0, v1, vw);
        storeSet(2, u0, u1, v0, v1, uw, vw);
    }
    __syncthreads();   // B1

    auto sampleMap = [&](const float* __restrict__ mapB, int C, int HW, int Wd, int set,
                         _Float16* dst) {
        const int pt = t & 127, hs = t >> 7;
        const int x0 = sIdx[set * 512 + pt], x1 = sIdx[set * 512 + 128 + pt];
        const int y0 = sIdx[set * 512 + 256 + pt], y1 = sIdx[set * 512 + 384 + pt];
        const float wx = sWgt[set * 256 + pt], wy = sWgt[set * 256 + 128 + pt];
        const float w00 = (1.0f - wx) * (1.0f - wy), w01 = wx * (1.0f - wy);
        const float w10 = (1.0f - wx) * wy, w11 = wx * wy;
        const int i00 = y0 * Wd + x0, i01 = y0 * Wd + x1, i10 = y1 * Wd + x0, i11 = y1 * Wd + x1;
        const int np = C >> 2;
#pragma unroll 4
        for (int i = 0; i < np; ++i) {
            const int c0 = hs * (C >> 1) + 2 * i;
            const float* p0 = mapB + (size_t)c0 * HW;
            const float* p1 = p0 + HW;
            float v0 = p0[i00] * w00 + p0[i01] * w01 + p0[i10] * w10 + p0[i11] * w11;
            float v1 = p1[i00] * w00 + p1[i01] * w01 + p1[i10] * w10 + p1[i11] * w11;
            half2v hv; hv[0] = (_Float16)v0; hv[1] = (_Float16)v1;
            *reinterpret_cast<half2v*>(dst + pt * 128 + (c0 ^ swz(pt))) = hv;
        }
    };

    // ---------- sample f8 -> bufA, fctx -> bufB[:,0:64]
    sampleMap(feat_s8 + (size_t)b * 128 * 3072, 128, 3072, 64, 0, bufA);
    sampleMap(ctx_s8 + (size_t)b * 64 * 3072, 64, 3072, 64, 0, bufB);
    __syncthreads();   // B2

    // ---------- ctx: h2 = f8 + sig(g1)*(fctx @ ctx_w + ctx_b)   (bufB -> bufA)
    {
        floatx4 acc[8][2];
#pragma unroll
        for (int c = 0; c < 8; ++c) { acc[c][0] = (floatx4)0.0f; acc[c][1] = (floatx4)0.0f; }
        gemmT<2, 8>(acc, wsp + WS_CTX, 8, 0, 0, bufB, ptb, lane);
#pragma unroll
        for (int ct = 0; ct < 8; ++ct) {
            const int ch0 = ct * 16 + g * 4;
            const float4 bb = *reinterpret_cast<const float4*>(ctx_b + ch0);
            const float4 gg = *reinterpret_cast<const float4*>(gate1 + ch0);
            const float g0 = sigmoidf_(gg.x), g1v = sigmoidf_(gg.y),
                        g2v = sigmoidf_(gg.z), g3 = sigmoidf_(gg.w);
#pragma unroll
            for (int pr = 0; pr < 2; ++pr) {
                const int pt = ptb + pr * 16 + m;
                half4v rv = loadH4(bufA, pt, ch0);
                floatx4 v = acc[ct][pr];
                storeH4(bufA, pt, ch0,
                        (float)rv[0] + g0 * (v[0] + bb.x), (float)rv[1] + g1v * (v[1] + bb.y),
                        (float)rv[2] + g2v * (v[2] + bb.z), (float)rv[3] + g3 * (v[3] + bb.w));
            }
        }
    }

    // ---------- ffn1: bufA -> bufA (gelu h0 -> bufB, gelu h1 -> bufA; h2 dead)
    {
        {   // au0: W1 cols 0..127
            floatx4 au[8][2];
#pragma unroll
            for (int c = 0; c < 8; ++c) { au[c][0] = (floatx4)0.0f; au[c][1] = (floatx4)0.0f; }
            gemmT<4, 8>(au, wsp + WS_F1W1, 16, 0, 0, bufA, ptb, lane);
#pragma unroll
            for (int ct = 0; ct < 8; ++ct) {
                const int ch0 = ct * 16 + g * 4;
                const float4 bb = *reinterpret_cast<const float4*>(ffn1_b1 + ch0);
#pragma unroll
                for (int pr = 0; pr < 2; ++pr) {
                    const int pt = ptb + pr * 16 + m;
                    floatx4 v = au[ct][pr];
                    storeH4(bufB, pt, ch0, geluf_(v[0] + bb.x), geluf_(v[1] + bb.y),
                            geluf_(v[2] + bb.z), geluf_(v[3] + bb.w));
                }
            }
        }
        {   // au1: W1 cols 128..255 -> overwrite bufA (h2 dead; wave-private rows)
            floatx4 au[8][2];
#pragma unroll
            for (int c = 0; c < 8; ++c) { au[c][0] = (floatx4)0.0f; au[c][1] = (floatx4)0.0f; }
            gemmT<4, 8>(au, wsp + WS_F1W1, 16, 0, 8, bufA, ptb, lane);
#pragma unroll
            for (int ct = 0; ct < 8; ++ct) {
                const int ch0 = ct * 16 + g * 4;
                const float4 bb = *reinterpret_cast<const float4*>(ffn1_b1 + 128 + ch0);
#pragma unroll
                for (int pr = 0; pr < 2; ++pr) {
                    const int pt = ptb + pr * 16 + m;
                    floatx4 v = au[ct][pr];
                    storeH4(bufA, pt, ch0, geluf_(v[0] + bb.x), geluf_(v[1] + bb.y),
                            geluf_(v[2] + bb.z), geluf_(v[3] + bb.w));
                }
            }
        }
        {   // acc: W2 over bufB (k-tiles 0..3) + bufA (k-tiles 4..7) -> bufA
            floatx4 acc[8][2];
#pragma unroll
            for (int c = 0; c < 8; ++c) { acc[c][0] = (floatx4)0.0f; acc[c][1] = (floatx4)0.0f; }
            gemmT<4, 8>(acc, wsp + WS_F1W2, 8, 0, 0, bufB, ptb, lane);
            gemmT<4, 8>(acc, wsp + WS_F1W2, 8, 4, 0, bufA, ptb, lane);
#pragma unroll
            for (int ct = 0; ct < 8; ++ct) {
                const int ch0 = ct * 16 + g * 4;
                const float4 bb = *reinterpret_cast<const float4*>(ffn1_b2 + ch0);
#pragma unroll
                for (int pr = 0; pr < 2; ++pr) {
                    const int pt = ptb + pr * 16 + m;
                    floatx4 v = acc[ct][pr];
                    storeH4(bufA, pt, ch0, v[0] + bb.x, v[1] + bb.y, v[2] + bb.z, v[3] + bb.w);
                }
            }
        }
    }
    __syncthreads();   // B3

    // ---------- sample f16 -> bufB
    sampleMap(feat_s16 + (size_t)b * 128 * 768, 128, 768, 32, 1, bufB);
    __syncthreads();   // B4

    // ---------- s8: h3 = f16 + sig(g2)*(h2' @ s8_w + s8_b)   (bufA -> bufB)
    {
        floatx4 acc[8][2];
#pragma unroll
        for (int c = 0; c < 8; ++c) { acc[c][0] = (floatx4)0.0f; acc[c][1] = (floatx4)0.0f; }
        gemmT<4, 8>(acc, wsp + WS_S8, 8, 0, 0, bufA, ptb, lane);
#pragma unroll
        for (int ct = 0; ct < 8; ++ct) {
            const int ch0 = ct * 16 + g * 4;
            const float4 bb = *reinterpret_cast<const float4*>(s8_b + ch0);
            const float4 gg = *reinterpret_cast<const float4*>(gate2 + ch0);
            const float g0 = sigmoidf_(gg.x), g1v = sigmoidf_(gg.y),
                        g2v = sigmoidf_(gg.z), g3 = sigmoidf_(gg.w);
#pragma unroll
            for (int pr = 0; pr < 2; ++pr) {
                const int pt = ptb + pr * 16 + m;
                half4v rv = loadH4(bufB, pt, ch0);
                floatx4 v = acc[ct][pr];
                storeH4(bufB, pt, ch0,
                        (float)rv[0] + g0 * (v[0] + bb.x), (float)rv[1] + g1v * (v[1] + bb.y),
                        (float)rv[2] + g2v * (v[2] + bb.z), (float)rv[3] + g3 * (v[3] + bb.w));
            }
        }
    }

    // ---------- ffn2: bufB -> bufB (gelu h0 -> bufA, gelu h1 -> bufB; h3 dead)
    {
        {   // au0
            floatx4 au[8][2];
#pragma unroll
            for (int c = 0; c < 8; ++c) { au[c][0] = (floatx4)0.0f; au[c][1] = (floatx4)0.0f; }
            gemmT<4, 8>(au, wsp + WS_F2W1, 16, 0, 0, bufB, ptb, lane);
#pragma unroll
            for (int ct = 0; ct < 8; ++ct) {
                const int ch0 = ct * 16 + g * 4;
                const float4 bb = *reinterpret_cast<const float4*>(ffn2_b1 + ch0);
#pragma unroll
                for (int pr = 0; pr < 2; ++pr) {
                    const int pt = ptb + pr * 16 + m;
                    floatx4 v = au[ct][pr];
                    storeH4(bufA, pt, ch0, geluf_(v[0] + bb.x), geluf_(v[1] + bb.y),
                            geluf_(v[2] + bb.z), geluf_(v[3] + bb.w));
                }
            }
        }
        {   // au1 -> overwrite bufB (h3 dead; wave-private rows)
            floatx4 au[8][2];
#pragma unroll
            for (int c = 0; c < 8; ++c) { au[c][0] = (floatx4)0.0f; au[c][1] = (floatx4)0.0f; }
            gemmT<4, 8>(au, wsp + WS_F2W1, 16, 0, 8, bufB, ptb, lane);
#pragma unroll
            for (int ct = 0; ct < 8; ++ct) {
                const int ch0 = ct * 16 + g * 4;
                const float4 bb = *reinterpret_cast<const float4*>(ffn2_b1 + 128 + ch0);
#pragma unroll
                for (int pr = 0; pr < 2; ++pr) {
                    const int pt = ptb + pr * 16 + m;
                    floatx4 v = au[ct][pr];
                    storeH4(bufB, pt, ch0, geluf_(v[0] + bb.x), geluf_(v[1] + bb.y),
                            geluf_(v[2] + bb.z), geluf_(v[3] + bb.w));
                }
            }
        }
        {   // acc: W2 over bufA (k 0..3) + bufB (k 4..7) -> bufB (fused)
            floatx4 acc[8][2];
#pragma unroll
            for (int c = 0; c < 8; ++c) { acc[c][0] = (floatx4)0.0f; acc[c][1] = (floatx4)0.0f; }
            gemmT<4, 8>(acc, wsp + WS_F2W2, 8, 0, 0, bufA, ptb, lane);
            gemmT<4, 8>(acc, wsp + WS_F2W2, 8, 4, 0, bufB, ptb, lane);
#pragma unroll
            for (int ct = 0; ct < 8; ++ct) {
                const int ch0 = ct * 16 + g * 4;
                const float4 bb = *reinterpret_cast<const float4*>(ffn2_b2 + ch0);
#pragma unroll
                for (int pr = 0; pr < 2; ++pr) {
                    const int pt = ptb + pr * 16 + m;
                    floatx4 v = acc[ct][pr];
                    storeH4(bufB, pt, ch0, v[0] + bb.x, v[1] + bb.y, v[2] + bb.z, v[3] + bb.w);
                }
            }
        }
    }
    __syncthreads();   // B5

    // ---------- sample f1w -> bufA
    sampleMap(feat1_s8 + (size_t)b * 128 * 3072, 128, 3072, 64, 2, bufA);
    __syncthreads();   // B6

    // ---------- head1 (260->256 relu), two 8-tile halves; f1w in register frags
    {
        half8 fw[4][2];
        loadFrags(fw, bufA, ptb, lane);   // wave-private rows; frees bufA for output
#pragma unroll
        for (int hf = 0; hf < 2; ++hf) {
            floatx4 acc[8][2];
#pragma unroll
            for (int c = 0; c < 8; ++c) { acc[c][0] = (floatx4)0.0f; acc[c][1] = (floatx4)0.0f; }
            gemmT<4, 8>(acc, wsp + WS_HW1, 16, 0, hf * 8, bufB, ptb, lane);      // fused rows 0..127
            gemmRegB<4, 8>(acc, wsp + WS_HW1, 16, 4, hf * 8, fw, lane);          // f1w rows 128..255
#pragma unroll
            for (int ct = 0; ct < 8; ++ct) {
                const int ch0 = ct * 16 + g * 4;
#pragma unroll
                for (int jj = 0; jj < 4; ++jj) {                                  // scal rows 256..259
                    const float4 wj = *reinterpret_cast<const float4*>(
                        hw1 + (size_t)(256 + jj) * 256 + hf * 128 + ch0);
#pragma unroll
                    for (int pr = 0; pr < 2; ++pr) {
                        const int pt = ptb + pr * 16 + m;
                        const float s = sScal[jj * 128 + pt];
                        floatx4 v = acc[ct][pr];
                        v[0] = fmaf(wj.x, s, v[0]); v[1] = fmaf(wj.y, s, v[1]);
                        v[2] = fmaf(wj.z, s, v[2]); v[3] = fmaf(wj.w, s, v[3]);
                        acc[ct][pr] = v;
                    }
                }
                const float4 bb = *reinterpret_cast<const float4*>(hb1 + hf * 128 + ch0);
                _Float16* dst = hf ? bufB : bufA;
#pragma unroll
                for (int pr = 0; pr < 2; ++pr) {
                    const int pt = ptb + pr * 16 + m;
                    floatx4 v = acc[ct][pr];
                    storeH4(dst, pt, ch0, fmaxf(v[0] + bb.x, 0.0f), fmaxf(v[1] + bb.y, 0.0f),
                            fmaxf(v[2] + bb.z, 0.0f), fmaxf(v[3] + bb.w, 0.0f));
                }
            }
        }
    }

    // ---------- head2 (256->128 relu): a1 lo=bufA, hi=bufB -> bufA
    {
        floatx4 acc[8][2];
#pragma unroll
        for (int c = 0; c < 8; ++c) { acc[c][0] = (floatx4)0.0f; acc[c][1] = (floatx4)0.0f; }
        gemmT<4, 8>(acc, wsp + WS_HW2, 8, 0, 0, bufA, ptb, lane);
        gemmT<4, 8>(acc, wsp + WS_HW2, 8, 4, 0, bufB, ptb, lane);
#pragma unroll
        for (int ct = 0; ct < 8; ++ct) {
            const int ch0 = ct * 16 + g * 4;
            const float4 bb = *reinterpret_cast<const float4*>(hb2 + ch0);
#pragma unroll
            for (int pr = 0; pr < 2; ++pr) {
                const int pt = ptb + pr * 16 + m;
                floatx4 v = acc[ct][pr];
                storeH4(bufA, pt, ch0, fmaxf(v[0] + bb.x, 0.0f), fmaxf(v[1] + bb.y, 0.0f),
                        fmaxf(v[2] + bb.z, 0.0f), fmaxf(v[3] + bb.w, 0.0f));
            }
        }
    }

    // ---------- head3 (128->64 relu): bufA -> bufB[:,0:64]
    {
        floatx4 acc[4][2];
#pragma unroll
        for (int c = 0; c < 4; ++c) { acc[c][0] = (floatx4)0.0f; acc[c][1] = (floatx4)0.0f; }
        gemmT<4, 4>(acc, wsp + WS_HW3, 4, 0, 0, bufA, ptb, lane);
#pragma unroll
        for (int ct = 0; ct < 4; ++ct) {
            const int ch0 = ct * 16 + g * 4;
            const float4 bb = *reinterpret_cast<const float4*>(hb3 + ch0);
#pragma unroll
            for (int pr = 0; pr < 2; ++pr) {
                const int pt = ptb + pr * 16 + m;
                floatx4 v = acc[ct][pr];
                storeH4(bufB, pt, ch0, fmaxf(v[0] + bb.x, 0.0f), fmaxf(v[1] + bb.y, 0.0f),
                        fmaxf(v[2] + bb.z, 0.0f), fmaxf(v[3] + bb.w, 0.0f));
            }
        }
    }
    __syncthreads();   // B7

    // ---------- head4 (64->2) fp32 + flow combine + store
    {
        const int pp = t >> 1, j = t & 1;
        float d = hb4[j];
#pragma unroll
        for (int i8 = 0; i8 < 8; ++i8) {
            const int c0 = i8 * 8;
            half8 hv = *reinterpret_cast<const half8*>(bufB + pp * 128 + (c0 ^ swz(pp)));
#pragma unroll
            for (int j2 = 0; j2 < 8; ++j2)
                d = fmaf((float)hv[j2], hw4[(c0 + j2) * 2 + j], d);
        }
        const int q = qbase + pp;
        const int rem = q - b * PTS_PER_IMG;
        const int gy = rem >> 9, gx = rem & 511;
        const float flow = sCps[j * 128 + pp] + d * (j == 0 ? 512.0f : 384.0f);
        out[(((size_t)b * 2 + j) * 384 + gy) * 512 + gx] = flow;
    }
}

extern "C" void kernel_launch(void* const* d_in, const int* in_sizes, int n_in,
                              void* d_out, int out_size, void* d_ws, size_t ws_size,
                              hipStream_t stream) {
    const float* feat_s8 = (const float*)d_in[1];
    const float* feat1_s8 = (const float*)d_in[2];
    const float* feat_s16 = (const float*)d_in[3];
    const float* ctx_s8 = (const float*)d_in[4];
    const float* coarse_flow = (const float*)d_in[5];
    const float* ctx_w = (const float*)d_in[6];
    const float* ctx_b = (const float*)d_in[7];
    const float* gate1 = (const float*)d_in[8];
    const float* ffn1_w1 = (const float*)d_in[9];
    const float* ffn1_b1 = (const float*)d_in[10];
    const float* ffn1_w2 = (const float*)d_in[11];
    const float* ffn1_b2 = (const float*)d_in[12];
    const float* s8_w = (const float*)d_in[13];
    const float* s8_b = (const float*)d_in[14];
    const float* gate2 = (const float*)d_in[15];
    const float* ffn2_w1 = (const float*)d_in[16];
    const float* ffn2_b1 = (const float*)d_in[17];
    const float* ffn2_w2 = (const float*)d_in[18];
    const float* ffn2_b2 = (const float*)d_in[19];
    const float* hw1 = (const float*)d_in[20];
    const float* hb1 = (const float*)d_in[21];
    const float* hw2 = (const float*)d_in[22];
    const float* hb2 = (const float*)d_in[23];
    const float* hw3 = (const float*)d_in[24];
    const float* hb3 = (const float*)d_in[25];
    const float* hw4 = (const float*)d_in[26];
    const float* hb4 = (const float*)d_in[27];
    float* out = (float*)d_out;
    _Float16* wsp = (_Float16*)d_ws;

    prepack_kernel<<<dim3(512), dim3(64), 0, stream>>>(
        ctx_w, ffn1_w1, ffn1_w2, s8_w, ffn2_w1, ffn2_w2, hw1, hw2, hw3, wsp);

    ifd_mfma<<<dim3(NBLOCKS), dim3(256), 0, stream>>>(
        feat_s8, feat1_s8, feat_s16, ctx_s8, coarse_flow,
        ctx_b, gate1, ffn1_b1, ffn1_b2, s8_b, gate2, ffn2_b1, ffn2_b2,
        hw1, hb1, hb2, hb3, hw4, hb4, wsp, out);
}